// Round 1
// baseline (22040.150 us; speedup 1.0000x reference)
//
#include <hip/hip_runtime.h>
#include <stdint.h>

typedef long long ll;
typedef unsigned long long ull;

// ---- problem dims ----
#define BB 64
#define L0 15958
#define L1 15918
#define P1 5306
#define L2 5226
#define P2 1742
#define L3 1662
#define P3 554
#define L4 474
#define P4 158
#define L5 78
#define EMB 9984

// ---- ws layout (bytes) ----
#define SO_BN0 0
#define SO_BN1 64
#define SO_BN2 1088
#define SO_BN3 2112
#define SO_BN4 4160
#define SO_BN5 6208
#define SO_SC1 8256
#define SO_SH1 8512
#define SO_SC2 8768
#define SO_SH2 9024
#define SO_SC3 9280
#define SO_SH3 9792
#define SO_SC4 10304
#define SO_SH4 10816
#define SO_SC5 11328
#define SO_SH5 11840
#define SO_SC6 12352
#define SO_SH6 20544
#define SO_SC7 28736
#define SO_SH7 32736
#define STATS_BYTES 65536ull

#define OFF_SW1F 65536ull
#define OFF_SW2  98304ull
#define OFF_SW3  266240ull
#define OFF_SW4  602112ull
#define OFF_SW5  1273856ull
#define OFF_SFW1 1945600ull
#define OFF_SFW2 22392832ull
#define OFF_A    25165824ull
#define OFF_B    54525952ull
#define OFF_C    100663296ull
#define WS_NEED  109051904ull

__device__ __forceinline__ int8_t fsign(float v) {
  return (v > 0.f) ? (int8_t)1 : ((v < 0.f) ? (int8_t)(-1) : (int8_t)0);
}

// ---- binarize a float tensor to int8 sign ----
__global__ void k_sign8(const float* __restrict__ w, int8_t* __restrict__ o, int n) {
  int stride = gridDim.x * blockDim.x;
  for (int i = blockIdx.x * blockDim.x + threadIdx.x; i < n; i += stride) {
    float v = w[i];
    o[i] = (v > 0.f) ? 1 : ((v < 0.f) ? -1 : 0);
  }
}

// ---- bn0 stats: per-channel (3) sum/sumsq over (B, L0) ----
__global__ __launch_bounds__(256) void k_bn0_stats(const float* __restrict__ x,
                                                   double* __restrict__ st) {
  const int r = blockIdx.x;            // b*3 + c, 0..191
  const int c = r % 3;
  const float* p = x + (size_t)r * L0;
  double s = 0.0, s2 = 0.0;
  for (int i = threadIdx.x; i < L0; i += 256) {
    double v = (double)p[i];
    s += v; s2 += v * v;
  }
  __shared__ double rs[256], rq[256];
  rs[threadIdx.x] = s; rq[threadIdx.x] = s2;
  __syncthreads();
  for (int off = 128; off; off >>= 1) {
    if (threadIdx.x < off) {
      rs[threadIdx.x] += rs[threadIdx.x + off];
      rq[threadIdx.x] += rq[threadIdx.x + off];
    }
    __syncthreads();
  }
  if (threadIdx.x == 0) {
    atomicAdd(&st[2 * c], rs[0]);
    atomicAdd(&st[2 * c + 1], rq[0]);
  }
}

// ---- fold bn0 scale into sign(w1): sw1f[o][c][k] = sign(w1)*a_c ----
__global__ void k_prep_w1(const float* __restrict__ w1, const float* __restrict__ g0,
                          const double* __restrict__ st0, float* __restrict__ swf) {
  __shared__ float a[3];
  if (threadIdx.x < 3) {
    const double N = (double)BB * (double)L0;
    double m = st0[2 * threadIdx.x] / N;
    double v = st0[2 * threadIdx.x + 1] / N - m * m;
    a[threadIdx.x] = (float)((double)g0[threadIdx.x] * rsqrt(v + 1e-5));
  }
  __syncthreads();
  for (int i = threadIdx.x; i < 64 * 3 * 41; i += blockDim.x) {
    int c = (i / 41) % 3;
    float w = w1[i];
    float s = (w > 0.f) ? 1.f : ((w < 0.f) ? -1.f : 0.f);
    swf[i] = s * a[c];
  }
}

// ---- conv1 pass 1: compute outputs, accumulate bn1 sum/sumsq (values discarded) ----
__global__ __launch_bounds__(256) void k_conv1_stats(const float* __restrict__ x,
                                                     const float* __restrict__ swf,
                                                     double* __restrict__ st) {
  __shared__ float wl[64 * 123];
  __shared__ float xs[3][296];
  const int b = blockIdx.y;
  const int l0 = blockIdx.x * 256;
  for (int i = threadIdx.x; i < 64 * 123; i += 256) wl[i] = swf[i];
  for (int i = threadIdx.x; i < 3 * 296; i += 256) {
    int c = i / 296, j = i - c * 296;
    int gl = l0 + j;
    xs[c][j] = (gl < L0) ? x[((size_t)b * 3 + c) * L0 + gl] : 0.f;
  }
  __syncthreads();
  const int o = threadIdx.x >> 2, q = threadIdx.x & 3;
  const float* wo = wl + o * 123;
  float s = 0.f, s2 = 0.f;
  for (int j = 0; j < 64; ++j) {
    const int lloc = q + 4 * j;
    if (l0 + lloc >= L1) break;
    float acc = 0.f;
#pragma unroll
    for (int c = 0; c < 3; ++c) {
      const float* xc = &xs[c][lloc];
      const float* wc = wo + c * 41;
#pragma unroll
      for (int k = 0; k < 41; ++k) acc += xc[k] * wc[k];
    }
    s += acc;
    s2 += acc * acc;
  }
  s  += __shfl_xor(s, 1, 64);  s  += __shfl_xor(s, 2, 64);
  s2 += __shfl_xor(s2, 1, 64); s2 += __shfl_xor(s2, 2, 64);
  if (q == 0) {
    atomicAdd(&st[2 * o], (double)s);
    atomicAdd(&st[2 * o + 1], (double)s2);
  }
}

// ---- conv1 pass 2: recompute, bn1+htanh+maxpool3+sign -> int8 ----
__global__ __launch_bounds__(256) void k_conv1_pool(const float* __restrict__ x,
                                                    const float* __restrict__ swf,
                                                    const float* __restrict__ sc,
                                                    const float* __restrict__ sh,
                                                    int8_t* __restrict__ out) {
  __shared__ float wl[64 * 123];
  __shared__ float xs[3][232];
  const int b = blockIdx.y;
  const int p0 = blockIdx.x * 64;
  const int l0 = p0 * 3;
  for (int i = threadIdx.x; i < 64 * 123; i += 256) wl[i] = swf[i];
  for (int i = threadIdx.x; i < 3 * 232; i += 256) {
    int c = i / 232, j = i - c * 232;
    int gl = l0 + j;
    xs[c][j] = (gl < L0) ? x[((size_t)b * 3 + c) * L0 + gl] : 0.f;
  }
  __syncthreads();
  const int o = threadIdx.x >> 2, q = threadIdx.x & 3;
  const float scale = sc[o], shift = sh[o];
  for (int j = 0; j < 16; ++j) {
    const int pl = q + 4 * j;
    const int p = p0 + pl;
    if (p >= P1) break;
    float m = -3.4e38f;
#pragma unroll
    for (int r = 0; r < 3; ++r) {
      const int lloc = 3 * pl + r;
      float acc = 0.f;
#pragma unroll
      for (int c = 0; c < 3; ++c) {
        const float* xc = &xs[c][lloc];
        const float* wc = wl + o * 123 + c * 41;
#pragma unroll
        for (int k = 0; k < 41; ++k) acc += xc[k] * wc[k];
      }
      m = fmaxf(m, acc * scale + shift);
    }
    out[((size_t)b * 64 + o) * P1 + p] = fsign(m);
  }
}

// ---- finalize BN (double stats) -> scale/shift ----
__global__ void k_finalize_d(const double* __restrict__ st, const float* __restrict__ g,
                             const float* __restrict__ bb, float* __restrict__ sc,
                             float* __restrict__ sh, int C, double invN) {
  int c = blockIdx.x * blockDim.x + threadIdx.x;
  if (c >= C) return;
  double m = st[2 * c] * invN;
  double v = st[2 * c + 1] * invN - m * m;
  double s = (double)g[c] * rsqrt(v + 1e-5);
  sc[c] = (float)s;
  sh[c] = (float)((double)bb[c] - m * s);
}

// ---- finalize BN (int64 stats) ----
__global__ void k_finalize_ll(const ll* __restrict__ st, const float* __restrict__ g,
                              const float* __restrict__ bb, float* __restrict__ sc,
                              float* __restrict__ sh, int C, double invN) {
  int c = blockIdx.x * blockDim.x + threadIdx.x;
  if (c >= C) return;
  double m = (double)st[2 * c] * invN;
  double v = (double)st[2 * c + 1] * invN - m * m;
  double s = (double)g[c] * rsqrt(v + 1e-5);
  sc[c] = (float)s;
  sh[c] = (float)((double)bb[c] - m * s);
}

// ---- binarized conv (dilation 2), int8 in/w -> int16 out, int64 stats ----
template <int CIN>
__global__ __launch_bounds__(256) void k_bconv(const int8_t* __restrict__ in,
                                               const int8_t* __restrict__ w,
                                               short* __restrict__ out,
                                               ull* __restrict__ st,
                                               int Lin, int Lout, int Cout) {
  __shared__ int8_t xs[CIN * 144];
  __shared__ int8_t wl[4 * CIN * 41];
  const int b = blockIdx.z;
  const int ob = blockIdx.y * 4;
  const int l0 = blockIdx.x * 64;
  for (int i = threadIdx.x; i < CIN * 144; i += 256) {
    int c = i / 144;
    int j = i - c * 144;
    int gl = l0 + j;
    xs[i] = (gl < Lin) ? in[((size_t)b * CIN + c) * Lin + gl] : (int8_t)0;
  }
  for (int i = threadIdx.x; i < 4 * CIN * 41; i += 256) {
    wl[i] = w[(size_t)ob * CIN * 41 + i];
  }
  __syncthreads();
  const int wave = threadIdx.x >> 6;
  const int lane = threadIdx.x & 63;
  const int o = ob + wave;
  const int l = l0 + lane;
  const int8_t* wo = wl + wave * CIN * 41;
  const int8_t* xb = xs + lane;
  int acc = 0;
  for (int c = 0; c < CIN; ++c) {
    const int8_t* xc = xb + c * 144;
    const int8_t* wc = wo + c * 41;
#pragma unroll
    for (int k = 0; k < 41; ++k) acc += (int)xc[2 * k] * (int)wc[k];
  }
  const bool valid = (l < Lout);
  if (valid) out[((size_t)b * Cout + o) * Lout + l] = (short)acc;
  int sv = valid ? acc : 0;
  int sq = valid ? acc * acc : 0;
  for (int off = 32; off; off >>= 1) {
    sv += __shfl_down(sv, off, 64);
    sq += __shfl_down(sq, off, 64);
  }
  if (lane == 0) {
    atomicAdd(&st[2 * o], (ull)(ll)sv);
    atomicAdd(&st[2 * o + 1], (ull)(ll)sq);
  }
}

// ---- bn + htanh + maxpool3 + sign (int16 in -> int8 out) ----
__global__ void k_pool(const short* __restrict__ h, int8_t* __restrict__ o,
                       const float* __restrict__ sc, const float* __restrict__ sh,
                       int C, int Lout, int Lp, int total) {
  int i = blockIdx.x * 256 + threadIdx.x;
  if (i >= total) return;
  int p = i % Lp;
  int t = i / Lp;
  int c = t % C;
  const short* hp = h + (size_t)t * Lout + 3 * p;
  float s = sc[c], b = sh[c];
  float y0 = (float)hp[0] * s + b;
  float y1 = (float)hp[1] * s + b;
  float y2 = (float)hp[2] * s + b;
  o[i] = fsign(fmaxf(y0, fmaxf(y1, y2)));
}

// ---- bn + sign (no pool); c = (i/L)%C ----
template <typename T>
__global__ void k_bn_sign(const T* __restrict__ h, int8_t* __restrict__ o,
                          const float* __restrict__ sc, const float* __restrict__ sh,
                          int C, int L, int total) {
  int i = blockIdx.x * 256 + threadIdx.x;
  if (i >= total) return;
  int c = (i / L) % C;
  float y = (float)h[i] * sc[c] + sh[c];
  o[i] = fsign(y);
}

// ---- binarized FC: out[b][f] = sum_i e[b][i]*w[f][i] ----
template <int K>
__global__ __launch_bounds__(256) void k_fc(const int8_t* __restrict__ e,
                                            const int8_t* __restrict__ w,
                                            int* __restrict__ out, int F) {
  __shared__ int es[K / 4];
  const int b = blockIdx.y;
  const int* ep = (const int*)(e + (size_t)b * K);
  for (int i = threadIdx.x; i < K / 4; i += 256) es[i] = ep[i];
  __syncthreads();
  const int f = blockIdx.x * 256 + threadIdx.x;
  if (f >= F) return;
  const int* wp = (const int*)(w + (size_t)f * K);
  int acc = 0;
  for (int i = 0; i < K / 4; ++i) {
    int wd = wp[i], ed = es[i];
    acc += (int)(int8_t)(wd) * (int)(int8_t)(ed)
         + (int)(int8_t)(wd >> 8) * (int)(int8_t)(ed >> 8)
         + (int)(int8_t)(wd >> 16) * (int)(int8_t)(ed >> 16)
         + (int)(wd >> 24) * (int)(ed >> 24);
  }
  out[(size_t)b * F + f] = acc;
}

// ---- FC batchnorm stats over batch (N=64) -> scale/shift directly ----
__global__ void k_fcstats(const int* __restrict__ fc, const float* __restrict__ g,
                          const float* __restrict__ bb, float* __restrict__ sc,
                          float* __restrict__ sh, int F) {
  int f = blockIdx.x * blockDim.x + threadIdx.x;
  if (f >= F) return;
  double s = 0.0, q = 0.0;
  for (int b = 0; b < BB; ++b) {
    double v = (double)fc[(size_t)b * F + f];
    s += v; q += v * v;
  }
  double m = s / 64.0;
  double v = q / 64.0 - m * m;
  double scd = (double)g[f] * rsqrt(v + 1e-5);
  sc[f] = (float)scd;
  sh[f] = (float)((double)bb[f] - m * scd);
}

// ---- bn7 + log_softmax, one block per batch row ----
__global__ __launch_bounds__(256) void k_lsm(const int* __restrict__ fc,
                                             const float* __restrict__ sc,
                                             const float* __restrict__ sh,
                                             float* __restrict__ out) {
  __shared__ float y[1000];
  __shared__ float red[256];
  const int b = blockIdx.x;
  float lm = -3.4e38f;
  for (int j = threadIdx.x; j < 1000; j += 256) {
    float v = (float)fc[b * 1000 + j] * sc[j] + sh[j];
    y[j] = v;
    lm = fmaxf(lm, v);
  }
  red[threadIdx.x] = lm;
  __syncthreads();
  for (int off = 128; off; off >>= 1) {
    if (threadIdx.x < off) red[threadIdx.x] = fmaxf(red[threadIdx.x], red[threadIdx.x + off]);
    __syncthreads();
  }
  const float M = red[0];
  __syncthreads();
  float ls = 0.f;
  for (int j = threadIdx.x; j < 1000; j += 256) ls += expf(y[j] - M);
  red[threadIdx.x] = ls;
  __syncthreads();
  for (int off = 128; off; off >>= 1) {
    if (threadIdx.x < off) red[threadIdx.x] += red[threadIdx.x + off];
    __syncthreads();
  }
  const float L = M + logf(red[0]);
  for (int j = threadIdx.x; j < 1000; j += 256) out[b * 1000 + j] = y[j] - L;
}

extern "C" void kernel_launch(void* const* d_in, const int* in_sizes, int n_in,
                              void* d_out, int out_size, void* d_ws, size_t ws_size,
                              hipStream_t stream) {
  if (ws_size < WS_NEED) return;  // workspace too small; fail visibly
  char* ws = (char*)d_ws;

  const float* x   = (const float*)d_in[0];
  const float* g0  = (const float*)d_in[1];
  const float* w1  = (const float*)d_in[3];
  const float* g1  = (const float*)d_in[5];
  const float* b1  = (const float*)d_in[6];
  const float* w2  = (const float*)d_in[7];
  const float* g2  = (const float*)d_in[9];
  const float* b2  = (const float*)d_in[10];
  const float* w3  = (const float*)d_in[11];
  const float* g3  = (const float*)d_in[13];
  const float* b3  = (const float*)d_in[14];
  const float* w4  = (const float*)d_in[15];
  const float* g4  = (const float*)d_in[17];
  const float* b4  = (const float*)d_in[18];
  const float* w5  = (const float*)d_in[19];
  const float* g5  = (const float*)d_in[21];
  const float* b5  = (const float*)d_in[22];
  const float* fw1 = (const float*)d_in[23];
  const float* g6  = (const float*)d_in[25];
  const float* b6  = (const float*)d_in[26];
  const float* fw2 = (const float*)d_in[27];
  const float* g7  = (const float*)d_in[29];
  const float* b7  = (const float*)d_in[30];
  float* out = (float*)d_out;

  double* st0 = (double*)(ws + SO_BN0);
  double* st1 = (double*)(ws + SO_BN1);
  ull* st2 = (ull*)(ws + SO_BN2);
  ull* st3 = (ull*)(ws + SO_BN3);
  ull* st4 = (ull*)(ws + SO_BN4);
  ull* st5 = (ull*)(ws + SO_BN5);
  float* sc1 = (float*)(ws + SO_SC1); float* sh1 = (float*)(ws + SO_SH1);
  float* sc2 = (float*)(ws + SO_SC2); float* sh2 = (float*)(ws + SO_SH2);
  float* sc3 = (float*)(ws + SO_SC3); float* sh3 = (float*)(ws + SO_SH3);
  float* sc4 = (float*)(ws + SO_SC4); float* sh4 = (float*)(ws + SO_SH4);
  float* sc5 = (float*)(ws + SO_SC5); float* sh5 = (float*)(ws + SO_SH5);
  float* sc6 = (float*)(ws + SO_SC6); float* sh6 = (float*)(ws + SO_SH6);
  float* sc7 = (float*)(ws + SO_SC7); float* sh7 = (float*)(ws + SO_SH7);

  float* sw1f = (float*)(ws + OFF_SW1F);
  int8_t* sw2 = (int8_t*)(ws + OFF_SW2);
  int8_t* sw3 = (int8_t*)(ws + OFF_SW3);
  int8_t* sw4 = (int8_t*)(ws + OFF_SW4);
  int8_t* sw5 = (int8_t*)(ws + OFF_SW5);
  int8_t* sfw1 = (int8_t*)(ws + OFF_SFW1);
  int8_t* sfw2 = (int8_t*)(ws + OFF_SFW2);

  int8_t* h1p = (int8_t*)(ws + OFF_A);
  short*  h2  = (short*)(ws + OFF_B);
  int8_t* h2p = (int8_t*)(ws + OFF_C);
  short*  h3  = (short*)(ws + OFF_A);
  int8_t* h3p = (int8_t*)(ws + OFF_B);
  short*  h4  = (short*)(ws + OFF_C);
  int8_t* h4p = (int8_t*)(ws + OFF_A);
  short*  h5  = (short*)(ws + OFF_B);
  int8_t* e1  = (int8_t*)(ws + OFF_C);
  int*    fc1o = (int*)(ws + OFF_A);
  int8_t* e2  = (int8_t*)(ws + OFF_B);
  int*    fc2o = (int*)(ws + OFF_C);

  hipMemsetAsync(ws, 0, STATS_BYTES, stream);

  // binarize weights
  k_sign8<<<1024, 256, 0, stream>>>(w2, sw2, 64 * 64 * 41);
  k_sign8<<<1024, 256, 0, stream>>>(w3, sw3, 128 * 64 * 41);
  k_sign8<<<1024, 256, 0, stream>>>(w4, sw4, 128 * 128 * 41);
  k_sign8<<<1024, 256, 0, stream>>>(w5, sw5, 128 * 128 * 41);
  k_sign8<<<2048, 256, 0, stream>>>(fw1, sfw1, 2048 * EMB);
  k_sign8<<<1024, 256, 0, stream>>>(fw2, sfw2, 1000 * 2048);

  // bn0 stats and folded conv1 weights
  k_bn0_stats<<<192, 256, 0, stream>>>(x, st0);
  k_prep_w1<<<1, 256, 0, stream>>>(w1, g0, st0, sw1f);

  // conv1: stats pass, finalize bn1, pooled/sign pass
  k_conv1_stats<<<dim3(63, 64), 256, 0, stream>>>(x, sw1f, st1);
  k_finalize_d<<<1, 64, 0, stream>>>(st1, g1, b1, sc1, sh1, 64, 1.0 / ((double)BB * L1));
  k_conv1_pool<<<dim3(83, 64), 256, 0, stream>>>(x, sw1f, sc1, sh1, h1p);

  // conv2
  k_bconv<64><<<dim3(82, 16, 64), 256, 0, stream>>>(h1p, sw2, h2, st2, P1, L2, 64);
  k_finalize_ll<<<1, 64, 0, stream>>>((const ll*)st2, g2, b2, sc2, sh2, 64, 1.0 / ((double)BB * L2));
  k_pool<<<(64 * 64 * P2 + 255) / 256, 256, 0, stream>>>(h2, h2p, sc2, sh2, 64, L2, P2, 64 * 64 * P2);

  // conv3
  k_bconv<64><<<dim3(26, 32, 64), 256, 0, stream>>>(h2p, sw3, h3, st3, P2, L3, 128);
  k_finalize_ll<<<1, 128, 0, stream>>>((const ll*)st3, g3, b3, sc3, sh3, 128, 1.0 / ((double)BB * L3));
  k_pool<<<(64 * 128 * P3 + 255) / 256, 256, 0, stream>>>(h3, h3p, sc3, sh3, 128, L3, P3, 64 * 128 * P3);

  // conv4
  k_bconv<128><<<dim3(8, 32, 64), 256, 0, stream>>>(h3p, sw4, h4, st4, P3, L4, 128);
  k_finalize_ll<<<1, 128, 0, stream>>>((const ll*)st4, g4, b4, sc4, sh4, 128, 1.0 / ((double)BB * L4));
  k_pool<<<(64 * 128 * P4 + 255) / 256, 256, 0, stream>>>(h4, h4p, sc4, sh4, 128, L4, P4, 64 * 128 * P4);

  // conv5 (no pool; bn5+htanh+sign -> e1)
  k_bconv<128><<<dim3(2, 32, 64), 256, 0, stream>>>(h4p, sw5, h5, st5, P4, L5, 128);
  k_finalize_ll<<<1, 128, 0, stream>>>((const ll*)st5, g5, b5, sc5, sh5, 128, 1.0 / ((double)BB * L5));
  k_bn_sign<short><<<(BB * EMB + 255) / 256, 256, 0, stream>>>(h5, e1, sc5, sh5, 128, L5, BB * EMB);

  // fc1 -> bn6 -> sign
  k_fc<EMB><<<dim3(8, 64), 256, 0, stream>>>(e1, sfw1, fc1o, 2048);
  k_fcstats<<<8, 256, 0, stream>>>(fc1o, g6, b6, sc6, sh6, 2048);
  k_bn_sign<int><<<(BB * 2048 + 255) / 256, 256, 0, stream>>>(fc1o, e2, sc6, sh6, 2048, 1, BB * 2048);

  // fc2 -> bn7 -> log_softmax
  k_fc<2048><<<dim3(4, 64), 256, 0, stream>>>(e2, sfw2, fc2o, 1000);
  k_fcstats<<<4, 256, 0, stream>>>(fc2o, g7, b7, sc7, sh7, 1000);
  k_lsm<<<64, 256, 0, stream>>>(fc2o, sc7, sh7, out);
}

// Round 2
// 3413.634 us; speedup vs baseline: 6.4565x; 6.4565x over previous
//
#include <hip/hip_runtime.h>
#include <stdint.h>

typedef long long ll;
typedef unsigned long long ull;
typedef int v4i __attribute__((ext_vector_type(4)));

// ---- problem dims ----
#define BB 64
#define L0 15958
#define L1 15918
#define P1 5306
#define L2 5226
#define P2 1742
#define L3 1662
#define P3 554
#define L4 474
#define P4 158
#define L5 78
#define EMB 9984

// ---- ws layout (bytes) ----
#define SO_BN0 0
#define SO_BN1 64
#define SO_BN2 1088
#define SO_BN3 2112
#define SO_BN4 4160
#define SO_BN5 6208
#define SO_SC1 8256
#define SO_SH1 8512
#define SO_SC2 8768
#define SO_SH2 9024
#define SO_SC3 9280
#define SO_SH3 9792
#define SO_SC4 10304
#define SO_SH4 10816
#define SO_SC5 11328
#define SO_SH5 11840
#define SO_SC6 12352
#define SO_SH6 20544
#define SO_SC7 28736
#define SO_SH7 32736
#define STATS_BYTES 65536ull

#define OFF_SW1F 65536ull
#define OFF_SW2  98304ull
#define OFF_SW3  266240ull
#define OFF_SW4  602112ull
#define OFF_SW5  1273856ull
#define OFF_SFW1 1945600ull
#define OFF_SFW2 22392832ull
#define OFF_A    25165824ull
#define OFF_B    54525952ull
#define OFF_C    100663296ull
#define WS_NEED  109051904ull

__device__ __forceinline__ int8_t fsign(float v) {
  return (v > 0.f) ? (int8_t)1 : ((v < 0.f) ? (int8_t)(-1) : (int8_t)0);
}

// ---- binarize a float tensor to int8 sign (layout-preserving) ----
__global__ void k_sign8(const float* __restrict__ w, int8_t* __restrict__ o, int n) {
  int stride = gridDim.x * blockDim.x;
  for (int i = blockIdx.x * blockDim.x + threadIdx.x; i < n; i += stride) {
    float v = w[i];
    o[i] = (v > 0.f) ? 1 : ((v < 0.f) ? -1 : 0);
  }
}

// ---- pack conv weights: w[o][c][t] fp32 -> sign int8 at [t][o][c] ----
__global__ void k_prep_wconv(const float* __restrict__ w, int8_t* __restrict__ o,
                             int COUT, int CIN) {
  int n = COUT * CIN * 41;
  int stride = gridDim.x * blockDim.x;
  for (int i = blockIdx.x * blockDim.x + threadIdx.x; i < n; i += stride) {
    int oc = i / (CIN * 41);
    int r = i - oc * CIN * 41;
    int c = r / 41;
    int t = r - c * 41;
    float v = w[i];
    int8_t s = (v > 0.f) ? 1 : ((v < 0.f) ? -1 : 0);
    o[((size_t)t * COUT + oc) * CIN + c] = s;
  }
}

// ---- bn0 stats: per-channel (3) sum/sumsq over (B, L0) ----
__global__ __launch_bounds__(256) void k_bn0_stats(const float* __restrict__ x,
                                                   double* __restrict__ st) {
  const int r = blockIdx.x;            // b*3 + c, 0..191
  const int c = r % 3;
  const float* p = x + (size_t)r * L0;
  double s = 0.0, s2 = 0.0;
  for (int i = threadIdx.x; i < L0; i += 256) {
    double v = (double)p[i];
    s += v; s2 += v * v;
  }
  __shared__ double rs[256], rq[256];
  rs[threadIdx.x] = s; rq[threadIdx.x] = s2;
  __syncthreads();
  for (int off = 128; off; off >>= 1) {
    if (threadIdx.x < off) {
      rs[threadIdx.x] += rs[threadIdx.x + off];
      rq[threadIdx.x] += rq[threadIdx.x + off];
    }
    __syncthreads();
  }
  if (threadIdx.x == 0) {
    atomicAdd(&st[2 * c], rs[0]);
    atomicAdd(&st[2 * c + 1], rq[0]);
  }
}

// ---- fold bn0 scale into sign(w1): sw1f[o][c][k] = sign(w1)*a_c ----
__global__ void k_prep_w1(const float* __restrict__ w1, const float* __restrict__ g0,
                          const double* __restrict__ st0, float* __restrict__ swf) {
  __shared__ float a[3];
  if (threadIdx.x < 3) {
    const double N = (double)BB * (double)L0;
    double m = st0[2 * threadIdx.x] / N;
    double v = st0[2 * threadIdx.x + 1] / N - m * m;
    a[threadIdx.x] = (float)((double)g0[threadIdx.x] * rsqrt(v + 1e-5));
  }
  __syncthreads();
  for (int i = threadIdx.x; i < 64 * 3 * 41; i += blockDim.x) {
    int c = (i / 41) % 3;
    float w = w1[i];
    float s = (w > 0.f) ? 1.f : ((w < 0.f) ? -1.f : 0.f);
    swf[i] = s * a[c];
  }
}

// ---- conv1 pass 1: compute outputs, accumulate bn1 sum/sumsq (values discarded) ----
__global__ __launch_bounds__(256) void k_conv1_stats(const float* __restrict__ x,
                                                     const float* __restrict__ swf,
                                                     double* __restrict__ st) {
  __shared__ float wl[64 * 123];
  __shared__ float xs[3][296];
  const int b = blockIdx.y;
  const int l0 = blockIdx.x * 256;
  for (int i = threadIdx.x; i < 64 * 123; i += 256) wl[i] = swf[i];
  for (int i = threadIdx.x; i < 3 * 296; i += 256) {
    int c = i / 296, j = i - c * 296;
    int gl = l0 + j;
    xs[c][j] = (gl < L0) ? x[((size_t)b * 3 + c) * L0 + gl] : 0.f;
  }
  __syncthreads();
  const int o = threadIdx.x >> 2, q = threadIdx.x & 3;
  const float* wo = wl + o * 123;
  float s = 0.f, s2 = 0.f;
  for (int j = 0; j < 64; ++j) {
    const int lloc = q + 4 * j;
    if (l0 + lloc >= L1) break;
    float acc = 0.f;
#pragma unroll
    for (int c = 0; c < 3; ++c) {
      const float* xc = &xs[c][lloc];
      const float* wc = wo + c * 41;
#pragma unroll
      for (int k = 0; k < 41; ++k) acc += xc[k] * wc[k];
    }
    s += acc;
    s2 += acc * acc;
  }
  s  += __shfl_xor(s, 1, 64);  s  += __shfl_xor(s, 2, 64);
  s2 += __shfl_xor(s2, 1, 64); s2 += __shfl_xor(s2, 2, 64);
  if (q == 0) {
    atomicAdd(&st[2 * o], (double)s);
    atomicAdd(&st[2 * o + 1], (double)s2);
  }
}

// ---- conv1 pass 2: recompute, bn1+htanh+maxpool3+sign -> int8 TRANSPOSED [b][p][64] ----
__global__ __launch_bounds__(256) void k_conv1_pool(const float* __restrict__ x,
                                                    const float* __restrict__ swf,
                                                    const float* __restrict__ sc,
                                                    const float* __restrict__ sh,
                                                    int8_t* __restrict__ out) {
  __shared__ float wl[64 * 123];
  __shared__ float xs[3][232];
  const int b = blockIdx.y;
  const int p0 = blockIdx.x * 64;
  const int l0 = p0 * 3;
  for (int i = threadIdx.x; i < 64 * 123; i += 256) wl[i] = swf[i];
  for (int i = threadIdx.x; i < 3 * 232; i += 256) {
    int c = i / 232, j = i - c * 232;
    int gl = l0 + j;
    xs[c][j] = (gl < L0) ? x[((size_t)b * 3 + c) * L0 + gl] : 0.f;
  }
  __syncthreads();
  const int o = threadIdx.x >> 2, q = threadIdx.x & 3;
  const float scale = sc[o], shift = sh[o];
  for (int j = 0; j < 16; ++j) {
    const int pl = q + 4 * j;
    const int p = p0 + pl;
    if (p >= P1) break;
    float m = -3.4e38f;
#pragma unroll
    for (int r = 0; r < 3; ++r) {
      const int lloc = 3 * pl + r;
      float acc = 0.f;
#pragma unroll
      for (int c = 0; c < 3; ++c) {
        const float* xc = &xs[c][lloc];
        const float* wc = wl + o * 123 + c * 41;
#pragma unroll
        for (int k = 0; k < 41; ++k) acc += xc[k] * wc[k];
      }
      m = fmaxf(m, acc * scale + shift);
    }
    out[((size_t)b * P1 + p) * 64 + o] = fsign(m);
  }
}

// ---- finalize BN (double stats) -> scale/shift ----
__global__ void k_finalize_d(const double* __restrict__ st, const float* __restrict__ g,
                             const float* __restrict__ bb, float* __restrict__ sc,
                             float* __restrict__ sh, int C, double invN) {
  int c = blockIdx.x * blockDim.x + threadIdx.x;
  if (c >= C) return;
  double m = st[2 * c] * invN;
  double v = st[2 * c + 1] * invN - m * m;
  double s = (double)g[c] * rsqrt(v + 1e-5);
  sc[c] = (float)s;
  sh[c] = (float)((double)bb[c] - m * s);
}

// ---- finalize BN (int64 stats) ----
__global__ void k_finalize_ll(const ll* __restrict__ st, const float* __restrict__ g,
                              const float* __restrict__ bb, float* __restrict__ sc,
                              float* __restrict__ sh, int C, double invN) {
  int c = blockIdx.x * blockDim.x + threadIdx.x;
  if (c >= C) return;
  double m = (double)st[2 * c] * invN;
  double v = (double)st[2 * c + 1] * invN - m * m;
  double s = (double)g[c] * rsqrt(v + 1e-5);
  sc[c] = (float)s;
  sh[c] = (float)((double)bb[c] - m * s);
}

// ---- MFMA binarized conv, dilation 2 ----
// xT: [B][Lin][CIN] int8 (channel-last), wp: [41][COUT][CIN] int8,
// hT: [B][Lout][COUT] int16. Block = 4 waves; wave = 16 out-ch x 64 positions.
template <int CIN, int COUT>
__global__ __launch_bounds__(256) void k_bconv_mfma(const int8_t* __restrict__ xT,
                                                    const int8_t* __restrict__ wp,
                                                    short* __restrict__ hT,
                                                    int Lin, int Lout) {
  const int b = blockIdx.z;
  const int l0 = blockIdx.x * 64;
  const int ro = blockIdx.y * 64 + (threadIdx.x >> 6) * 16;  // 16-row group
  const int lane = threadIdx.x & 63;
  const int r16 = lane & 15;   // A-row / B-col / D-col within fragment
  const int kg = lane >> 4;    // k-group (8-byte sub-block)

  v4i acc[4] = {v4i{0,0,0,0}, v4i{0,0,0,0}, v4i{0,0,0,0}, v4i{0,0,0,0}};

  const int8_t* xb = xT + (size_t)b * Lin * CIN + (size_t)(l0 + r16) * CIN + kg * 8;
  const int8_t* wb = wp + (size_t)(ro + r16) * CIN + kg * 8;

  for (int t = 0; t < 41; ++t) {
#pragma unroll
    for (int cc = 0; cc < CIN / 32; ++cc) {
      const int cb = cc * 32;
      long long a = *(const long long*)(wb + (size_t)t * COUT * CIN + cb);
      const int8_t* bp = xb + (size_t)(2 * t) * CIN + cb;
#pragma unroll
      for (int u = 0; u < 4; ++u) {
        long long bf = *(const long long*)(bp + (size_t)(16 * u) * CIN);
        acc[u] = __builtin_amdgcn_mfma_i32_16x16x32_i8(a, bf, acc[u], 0, 0, 0);
      }
    }
  }
#pragma unroll
  for (int u = 0; u < 4; ++u) {
    int p = l0 + 16 * u + r16;
    if (p < Lout) {
      short4 v;
      v.x = (short)acc[u][0]; v.y = (short)acc[u][1];
      v.z = (short)acc[u][2]; v.w = (short)acc[u][3];
      *(short4*)(hT + ((size_t)b * Lout + p) * COUT + ro + kg * 4) = v;
    }
  }
}

// ---- per-channel sum/sumsq over hT [rows][C] int16 ----
template <int C>
__global__ __launch_bounds__(256) void k_stats16(const short* __restrict__ hT,
                                                 ull* __restrict__ st, int rows) {
  const int tid = threadIdx.x;
  const int c = tid % C;
  const int phase = tid / C;
  const int RP = 256 / C;
  int chunk = (rows + gridDim.x - 1) / gridDim.x;
  int r0 = blockIdx.x * chunk;
  int r1 = r0 + chunk; if (r1 > rows) r1 = rows;
  ll s = 0, q = 0;
  for (int r = r0 + phase; r < r1; r += RP) {
    int v = hT[(size_t)r * C + c];
    s += v; q += (ll)v * v;
  }
  __shared__ ll ss[256], qq[256];
  ss[tid] = s; qq[tid] = q;
  __syncthreads();
  for (int off = 128; off >= C; off >>= 1) {
    if (tid < off) { ss[tid] += ss[tid + off]; qq[tid] += qq[tid + off]; }
    __syncthreads();
  }
  if (tid < C) {
    atomicAdd(&st[2 * tid], (ull)ss[tid]);
    atomicAdd(&st[2 * tid + 1], (ull)qq[tid]);
  }
}

// ---- bn + htanh + maxpool3 + sign: hT [b][Lout][C] int16 -> xT [b][Lp][C] int8 ----
__global__ void k_pool(const short* __restrict__ hT, int8_t* __restrict__ o,
                       const float* __restrict__ sc, const float* __restrict__ sh,
                       int C, int Lout, int Lp, int total) {
  int i = blockIdx.x * 256 + threadIdx.x;
  if (i >= total) return;
  int c = i % C;
  int t = i / C;
  int pp = t % Lp;
  int b = t / Lp;
  const short* hp = hT + ((size_t)b * Lout + 3 * pp) * C + c;
  float s = sc[c], bb = sh[c];
  float y0 = (float)hp[0] * s + bb;
  float y1 = (float)hp[C] * s + bb;
  float y2 = (float)hp[2 * C] * s + bb;
  o[i] = fsign(fmaxf(y0, fmaxf(y1, y2)));
}

// ---- conv5 epilogue: hT5 [b][78][128] -> e1 [b][c*78+p] (reference flatten order) ----
__global__ void k_bn_sign_t(const short* __restrict__ hT, int8_t* __restrict__ e,
                            const float* __restrict__ sc, const float* __restrict__ sh) {
  int i = blockIdx.x * 256 + threadIdx.x;
  if (i >= BB * 128 * L5) return;
  int p = i % L5;
  int c = (i / L5) % 128;
  int b = i / (L5 * 128);
  float y = (float)hT[((size_t)b * L5 + p) * 128 + c] * sc[c] + sh[c];
  e[i] = fsign(y);
}

// ---- bn + sign for FC activations (layout [b][F]) ----
__global__ void k_bn_sign_fc(const int* __restrict__ h, int8_t* __restrict__ o,
                             const float* __restrict__ sc, const float* __restrict__ sh,
                             int F, int total) {
  int i = blockIdx.x * 256 + threadIdx.x;
  if (i >= total) return;
  int c = i % F;
  float y = (float)h[i] * sc[c] + sh[c];
  o[i] = fsign(y);
}

// ---- binarized FC: out[b][f] = sum_i e[b][i]*w[f][i] ----
template <int K>
__global__ __launch_bounds__(256) void k_fc(const int8_t* __restrict__ e,
                                            const int8_t* __restrict__ w,
                                            int* __restrict__ out, int F) {
  __shared__ int es[K / 4];
  const int b = blockIdx.y;
  const int* ep = (const int*)(e + (size_t)b * K);
  for (int i = threadIdx.x; i < K / 4; i += 256) es[i] = ep[i];
  __syncthreads();
  const int f = blockIdx.x * 256 + threadIdx.x;
  if (f >= F) return;
  const int* wp = (const int*)(w + (size_t)f * K);
  int acc = 0;
  for (int i = 0; i < K / 4; ++i) {
    int wd = wp[i], ed = es[i];
    acc += (int)(int8_t)(wd) * (int)(int8_t)(ed)
         + (int)(int8_t)(wd >> 8) * (int)(int8_t)(ed >> 8)
         + (int)(int8_t)(wd >> 16) * (int)(int8_t)(ed >> 16)
         + (int)(wd >> 24) * (int)(ed >> 24);
  }
  out[(size_t)b * F + f] = acc;
}

// ---- FC batchnorm stats over batch (N=64) -> scale/shift directly ----
__global__ void k_fcstats(const int* __restrict__ fc, const float* __restrict__ g,
                          const float* __restrict__ bb, float* __restrict__ sc,
                          float* __restrict__ sh, int F) {
  int f = blockIdx.x * blockDim.x + threadIdx.x;
  if (f >= F) return;
  double s = 0.0, q = 0.0;
  for (int b = 0; b < BB; ++b) {
    double v = (double)fc[(size_t)b * F + f];
    s += v; q += v * v;
  }
  double m = s / 64.0;
  double v = q / 64.0 - m * m;
  double scd = (double)g[f] * rsqrt(v + 1e-5);
  sc[f] = (float)scd;
  sh[f] = (float)((double)bb[f] - m * scd);
}

// ---- bn7 + log_softmax, one block per batch row ----
__global__ __launch_bounds__(256) void k_lsm(const int* __restrict__ fc,
                                             const float* __restrict__ sc,
                                             const float* __restrict__ sh,
                                             float* __restrict__ out) {
  __shared__ float y[1000];
  __shared__ float red[256];
  const int b = blockIdx.x;
  float lm = -3.4e38f;
  for (int j = threadIdx.x; j < 1000; j += 256) {
    float v = (float)fc[b * 1000 + j] * sc[j] + sh[j];
    y[j] = v;
    lm = fmaxf(lm, v);
  }
  red[threadIdx.x] = lm;
  __syncthreads();
  for (int off = 128; off; off >>= 1) {
    if (threadIdx.x < off) red[threadIdx.x] = fmaxf(red[threadIdx.x], red[threadIdx.x + off]);
    __syncthreads();
  }
  const float M = red[0];
  __syncthreads();
  float ls = 0.f;
  for (int j = threadIdx.x; j < 1000; j += 256) ls += expf(y[j] - M);
  red[threadIdx.x] = ls;
  __syncthreads();
  for (int off = 128; off; off >>= 1) {
    if (threadIdx.x < off) red[threadIdx.x] += red[threadIdx.x + off];
    __syncthreads();
  }
  const float L = M + logf(red[0]);
  for (int j = threadIdx.x; j < 1000; j += 256) out[b * 1000 + j] = y[j] - L;
}

extern "C" void kernel_launch(void* const* d_in, const int* in_sizes, int n_in,
                              void* d_out, int out_size, void* d_ws, size_t ws_size,
                              hipStream_t stream) {
  if (ws_size < WS_NEED) return;
  char* ws = (char*)d_ws;

  const float* x   = (const float*)d_in[0];
  const float* g0  = (const float*)d_in[1];
  const float* w1  = (const float*)d_in[3];
  const float* g1  = (const float*)d_in[5];
  const float* b1  = (const float*)d_in[6];
  const float* w2  = (const float*)d_in[7];
  const float* g2  = (const float*)d_in[9];
  const float* b2  = (const float*)d_in[10];
  const float* w3  = (const float*)d_in[11];
  const float* g3  = (const float*)d_in[13];
  const float* b3  = (const float*)d_in[14];
  const float* w4  = (const float*)d_in[15];
  const float* g4  = (const float*)d_in[17];
  const float* b4  = (const float*)d_in[18];
  const float* w5  = (const float*)d_in[19];
  const float* g5  = (const float*)d_in[21];
  const float* b5  = (const float*)d_in[22];
  const float* fw1 = (const float*)d_in[23];
  const float* g6  = (const float*)d_in[25];
  const float* b6  = (const float*)d_in[26];
  const float* fw2 = (const float*)d_in[27];
  const float* g7  = (const float*)d_in[29];
  const float* b7  = (const float*)d_in[30];
  float* out = (float*)d_out;

  double* st0 = (double*)(ws + SO_BN0);
  double* st1 = (double*)(ws + SO_BN1);
  ull* st2 = (ull*)(ws + SO_BN2);
  ull* st3 = (ull*)(ws + SO_BN3);
  ull* st4 = (ull*)(ws + SO_BN4);
  ull* st5 = (ull*)(ws + SO_BN5);
  float* sc1 = (float*)(ws + SO_SC1); float* sh1 = (float*)(ws + SO_SH1);
  float* sc2 = (float*)(ws + SO_SC2); float* sh2 = (float*)(ws + SO_SH2);
  float* sc3 = (float*)(ws + SO_SC3); float* sh3 = (float*)(ws + SO_SH3);
  float* sc4 = (float*)(ws + SO_SC4); float* sh4 = (float*)(ws + SO_SH4);
  float* sc5 = (float*)(ws + SO_SC5); float* sh5 = (float*)(ws + SO_SH5);
  float* sc6 = (float*)(ws + SO_SC6); float* sh6 = (float*)(ws + SO_SH6);
  float* sc7 = (float*)(ws + SO_SC7); float* sh7 = (float*)(ws + SO_SH7);

  float* sw1f = (float*)(ws + OFF_SW1F);
  int8_t* wp2 = (int8_t*)(ws + OFF_SW2);
  int8_t* wp3 = (int8_t*)(ws + OFF_SW3);
  int8_t* wp4 = (int8_t*)(ws + OFF_SW4);
  int8_t* wp5 = (int8_t*)(ws + OFF_SW5);
  int8_t* sfw1 = (int8_t*)(ws + OFF_SFW1);
  int8_t* sfw2 = (int8_t*)(ws + OFF_SFW2);

  int8_t* h1p = (int8_t*)(ws + OFF_A);   // [64][P1][64]
  short*  h2  = (short*)(ws + OFF_B);    // [64][L2][64]
  int8_t* h2p = (int8_t*)(ws + OFF_C);   // [64][P2][64]
  short*  h3  = (short*)(ws + OFF_A);    // [64][L3][128]
  int8_t* h3p = (int8_t*)(ws + OFF_B);   // [64][P3][128]
  short*  h4  = (short*)(ws + OFF_C);    // [64][L4][128]
  int8_t* h4p = (int8_t*)(ws + OFF_A);   // [64][P4][128]
  short*  h5  = (short*)(ws + OFF_B);    // [64][L5][128]
  int8_t* e1  = (int8_t*)(ws + OFF_C);   // [64][EMB]
  int*    fc1o = (int*)(ws + OFF_A);
  int8_t* e2  = (int8_t*)(ws + OFF_B);
  int*    fc2o = (int*)(ws + OFF_C);

  hipMemsetAsync(ws, 0, STATS_BYTES, stream);

  // pack binarized weights
  k_prep_wconv<<<656, 256, 0, stream>>>(w2, wp2, 64, 64);
  k_prep_wconv<<<1024, 256, 0, stream>>>(w3, wp3, 128, 64);
  k_prep_wconv<<<1024, 256, 0, stream>>>(w4, wp4, 128, 128);
  k_prep_wconv<<<1024, 256, 0, stream>>>(w5, wp5, 128, 128);
  k_sign8<<<2048, 256, 0, stream>>>(fw1, sfw1, 2048 * EMB);
  k_sign8<<<1024, 256, 0, stream>>>(fw2, sfw2, 1000 * 2048);

  // bn0 stats and folded conv1 weights
  k_bn0_stats<<<192, 256, 0, stream>>>(x, st0);
  k_prep_w1<<<1, 256, 0, stream>>>(w1, g0, st0, sw1f);

  // conv1: stats pass, finalize bn1, pooled/sign pass (transposed output)
  k_conv1_stats<<<dim3(63, 64), 256, 0, stream>>>(x, sw1f, st1);
  k_finalize_d<<<1, 64, 0, stream>>>(st1, g1, b1, sc1, sh1, 64, 1.0 / ((double)BB * L1));
  k_conv1_pool<<<dim3(83, 64), 256, 0, stream>>>(x, sw1f, sc1, sh1, h1p);

  // conv2 (MFMA)
  k_bconv_mfma<64, 64><<<dim3(82, 1, 64), 256, 0, stream>>>(h1p, wp2, h2, P1, L2);
  k_stats16<64><<<256, 256, 0, stream>>>(h2, st2, BB * L2);
  k_finalize_ll<<<1, 64, 0, stream>>>((const ll*)st2, g2, b2, sc2, sh2, 64, 1.0 / ((double)BB * L2));
  k_pool<<<(BB * 64 * P2 + 255) / 256, 256, 0, stream>>>(h2, h2p, sc2, sh2, 64, L2, P2, BB * 64 * P2);

  // conv3
  k_bconv_mfma<64, 128><<<dim3(26, 2, 64), 256, 0, stream>>>(h2p, wp3, h3, P2, L3);
  k_stats16<128><<<256, 256, 0, stream>>>(h3, st3, BB * L3);
  k_finalize_ll<<<1, 128, 0, stream>>>((const ll*)st3, g3, b3, sc3, sh3, 128, 1.0 / ((double)BB * L3));
  k_pool<<<(BB * 128 * P3 + 255) / 256, 256, 0, stream>>>(h3, h3p, sc3, sh3, 128, L3, P3, BB * 128 * P3);

  // conv4
  k_bconv_mfma<128, 128><<<dim3(8, 2, 64), 256, 0, stream>>>(h3p, wp4, h4, P3, L4);
  k_stats16<128><<<256, 256, 0, stream>>>(h4, st4, BB * L4);
  k_finalize_ll<<<1, 128, 0, stream>>>((const ll*)st4, g4, b4, sc4, sh4, 128, 1.0 / ((double)BB * L4));
  k_pool<<<(BB * 128 * P4 + 255) / 256, 256, 0, stream>>>(h4, h4p, sc4, sh4, 128, L4, P4, BB * 128 * P4);

  // conv5 (no pool; bn5+htanh+sign -> e1, re-transposed to [b][c*78+p])
  k_bconv_mfma<128, 128><<<dim3(2, 2, 64), 256, 0, stream>>>(h4p, wp5, h5, P4, L5);
  k_stats16<128><<<256, 256, 0, stream>>>(h5, st5, BB * L5);
  k_finalize_ll<<<1, 128, 0, stream>>>((const ll*)st5, g5, b5, sc5, sh5, 128, 1.0 / ((double)BB * L5));
  k_bn_sign_t<<<(BB * EMB + 255) / 256, 256, 0, stream>>>(h5, e1, sc5, sh5);

  // fc1 -> bn6 -> sign
  k_fc<EMB><<<dim3(8, BB), 256, 0, stream>>>(e1, sfw1, fc1o, 2048);
  k_fcstats<<<8, 256, 0, stream>>>(fc1o, g6, b6, sc6, sh6, 2048);
  k_bn_sign_fc<<<(BB * 2048 + 255) / 256, 256, 0, stream>>>(fc1o, e2, sc6, sh6, 2048, BB * 2048);

  // fc2 -> bn7 -> log_softmax
  k_fc<2048><<<dim3(4, BB), 256, 0, stream>>>(e2, sfw2, fc2o, 1000);
  k_fcstats<<<4, 256, 0, stream>>>(fc2o, g7, b7, sc7, sh7, 1000);
  k_lsm<<<64, 256, 0, stream>>>(fc2o, sc7, sh7, out);
}

// Round 4
// 2474.072 us; speedup vs baseline: 8.9085x; 1.3798x over previous
//
#include <hip/hip_runtime.h>
#include <stdint.h>

typedef long long ll;
typedef unsigned long long ull;
typedef int v4i __attribute__((ext_vector_type(4)));

// ---- problem dims ----
#define BB 64
#define L0 15958
#define L1 15918
#define P1 5306
#define L2 5226
#define P2 1742
#define L3 1662
#define P3 554
#define L4 474
#define P4 158
#define L5 78
#define EMB 9984

// ---- ws layout (bytes) ----
// stats / scale-shift block (zeroed each launch)
#define SO_BN0 0
#define SO_BN1 64
#define SO_BN2 1088
#define SO_BN3 2112
#define SO_BN4 4160
#define SO_BN5 6208
#define SO_SC1 8256
#define SO_SH1 8512
#define SO_SC2 8768
#define SO_SH2 9024
#define SO_SC3 9280
#define SO_SH3 9792
#define SO_SC4 10304
#define SO_SH4 10816
#define SO_SC5 11328
#define SO_SH5 11840
#define SO_SC6 12352
#define SO_SH6 20544
#define SO_SC7 28736
#define SO_SH7 32736
#define STATS_BYTES 65536ull

// persistent through conv1 phase
#define OFF_W1T  65536ull        // 123*64*4 = 31488
#define OFF_H1P  98304ull        // 64*P1*64 = 21,733,376
#define OFF_MAXB 21831680ull     // 64*P1*64*4 = 86,933,504 (ends 108,765,184)

// phase-2 regions (alias the maxbuf span; used only after k_pool1)
#define OFF_WP2  21831680ull     // 41*64*64   = 167,936
#define OFF_WP3  21999616ull     // 41*128*64  = 335,872
#define OFF_WP4  22335488ull     // 41*128*128 = 671,744
#define OFF_WP5  23007232ull     // 671,744
#define OFF_SFW1 23678976ull     // 2048*9984  = 20,447,232
#define OFF_SFW2 44126208ull     // 1000*2048  = 2,048,000
#define OFF_X    46174208ull     // big ping (<= 42,811,392)
#define OFF_Y    88985600ull     // small pong (<= 7,131,136)
#define WS_NEED  109051904ull

__device__ __forceinline__ int8_t fsign(float v) {
  return (v > 0.f) ? (int8_t)1 : ((v < 0.f) ? (int8_t)(-1) : (int8_t)0);
}

// ---- binarize a float tensor to int8 sign (layout-preserving) ----
__global__ void k_sign8(const float* __restrict__ w, int8_t* __restrict__ o, int n) {
  int stride = gridDim.x * blockDim.x;
  for (int i = blockIdx.x * blockDim.x + threadIdx.x; i < n; i += stride) {
    float v = w[i];
    o[i] = (v > 0.f) ? 1 : ((v < 0.f) ? -1 : 0);
  }
}

// ---- pack conv weights: w[o][c][t] fp32 -> sign int8 at [t][o][c] ----
__global__ void k_prep_wconv(const float* __restrict__ w, int8_t* __restrict__ o,
                             int COUT, int CIN) {
  int n = COUT * CIN * 41;
  int stride = gridDim.x * blockDim.x;
  for (int i = blockIdx.x * blockDim.x + threadIdx.x; i < n; i += stride) {
    int oc = i / (CIN * 41);
    int r = i - oc * CIN * 41;
    int c = r / 41;
    int t = r - c * 41;
    float v = w[i];
    int8_t s = (v > 0.f) ? 1 : ((v < 0.f) ? -1 : 0);
    o[((size_t)t * COUT + oc) * CIN + c] = s;
  }
}

// ---- bn0 stats: per-channel (3) sum/sumsq over (B, L0) ----
__global__ __launch_bounds__(256) void k_bn0_stats(const float* __restrict__ x,
                                                   double* __restrict__ st) {
  const int r = blockIdx.x;            // b*3 + c, 0..191
  const int c = r % 3;
  const float* p = x + (size_t)r * L0;
  double s = 0.0, s2 = 0.0;
  for (int i = threadIdx.x; i < L0; i += 256) {
    double v = (double)p[i];
    s += v; s2 += v * v;
  }
  __shared__ double rs[256], rq[256];
  rs[threadIdx.x] = s; rq[threadIdx.x] = s2;
  __syncthreads();
  for (int off = 128; off; off >>= 1) {
    if (threadIdx.x < off) {
      rs[threadIdx.x] += rs[threadIdx.x + off];
      rq[threadIdx.x] += rq[threadIdx.x + off];
    }
    __syncthreads();
  }
  if (threadIdx.x == 0) {
    atomicAdd(&st[2 * c], rs[0]);
    atomicAdd(&st[2 * c + 1], rq[0]);
  }
}

// ---- fold bn0 scale into sign(w1), TRANSPOSED: wT[(c*41+k)*64 + o] = sign*a_c ----
__global__ void k_prep_w1T(const float* __restrict__ w1, const float* __restrict__ g0,
                           const double* __restrict__ st0, float* __restrict__ wT) {
  __shared__ float a[3];
  if (threadIdx.x < 3) {
    const double N = (double)BB * (double)L0;
    double m = st0[2 * threadIdx.x] / N;
    double v = st0[2 * threadIdx.x + 1] / N - m * m;
    a[threadIdx.x] = (float)((double)g0[threadIdx.x] * rsqrt(v + 1e-5));
  }
  __syncthreads();
  for (int i = threadIdx.x; i < 64 * 123; i += blockDim.x) {
    int o = i / 123;
    int r = i - o * 123;
    int c = r / 41;
    float w = w1[i];
    float s = (w > 0.f) ? 1.f : ((w < 0.f) ? -1.f : 0.f);
    wT[r * 64 + o] = s * a[c];
  }
}

// ---- fused conv1: register-blocked fp32 GEMM + bn1 stats + max3 pooling ----
// Block: 256 threads = 8 og * 32 lg; tile = 64 out-ch x 384 positions.
// Thread: 8 out-ch (og*8..+7) x 12 positions (lg*12..+11) = 4 aligned pools.
__global__ __launch_bounds__(256) void k_conv1_fused(const float* __restrict__ x,
                                                     const float* __restrict__ wT,
                                                     double* __restrict__ st,
                                                     float* __restrict__ maxb) {
  __shared__ float wl[123 * 64];
  __shared__ float xs[3][424];
  const int b = blockIdx.y;
  const int l0 = blockIdx.x * 384;
  for (int i = threadIdx.x; i < 123 * 64; i += 256) wl[i] = wT[i];
  for (int i = threadIdx.x; i < 3 * 424; i += 256) {
    int c = i / 424, j = i - c * 424;
    int gl = l0 + j;
    xs[c][j] = (gl < L0) ? x[((size_t)b * 3 + c) * L0 + gl] : 0.f;
  }
  __syncthreads();

  const int og = threadIdx.x >> 5;   // 0..7 -> out-ch og*8..+7
  const int lg = threadIdx.x & 31;   // 0..31 -> pos lg*12..+11
  const int lb = lg * 12;

  float acc[8][12];
#pragma unroll
  for (int j = 0; j < 8; ++j)
#pragma unroll
    for (int i = 0; i < 12; ++i) acc[j][i] = 0.f;

  const float4* wl4 = (const float4*)wl;
  for (int c = 0; c < 3; ++c) {
    const float* xr = &xs[c][lb];
    const int wbase = c * 41;
    for (int g = 0; g < 10; ++g) {
      float4 xq0 = *(const float4*)(xr + 4 * g);
      float4 xq1 = *(const float4*)(xr + 4 * g + 4);
      float4 xq2 = *(const float4*)(xr + 4 * g + 8);
      float4 xq3 = *(const float4*)(xr + 4 * g + 12);
      float xf[16] = {xq0.x, xq0.y, xq0.z, xq0.w, xq1.x, xq1.y, xq1.z, xq1.w,
                      xq2.x, xq2.y, xq2.z, xq2.w, xq3.x, xq3.y, xq3.z, xq3.w};
#pragma unroll
      for (int k4 = 0; k4 < 4; ++k4) {
        const int widx = ((wbase + 4 * g + k4) * 64 + og * 8) >> 2;
        float4 wa = wl4[widx];
        float4 wb = wl4[widx + 1];
        float wv[8] = {wa.x, wa.y, wa.z, wa.w, wb.x, wb.y, wb.z, wb.w};
#pragma unroll
        for (int j = 0; j < 8; ++j)
#pragma unroll
          for (int i = 0; i < 12; ++i)
            acc[j][i] = fmaf(wv[j], xf[k4 + i], acc[j][i]);
      }
    }
    {  // kk = 40 epilogue
      float4 xq0 = *(const float4*)(xr + 40);
      float4 xq1 = *(const float4*)(xr + 44);
      float4 xq2 = *(const float4*)(xr + 48);
      float xf[12] = {xq0.x, xq0.y, xq0.z, xq0.w, xq1.x, xq1.y, xq1.z, xq1.w,
                      xq2.x, xq2.y, xq2.z, xq2.w};
      const int widx = ((wbase + 40) * 64 + og * 8) >> 2;
      float4 wa = wl4[widx];
      float4 wb = wl4[widx + 1];
      float wv[8] = {wa.x, wa.y, wa.z, wa.w, wb.x, wb.y, wb.z, wb.w};
#pragma unroll
      for (int j = 0; j < 8; ++j)
#pragma unroll
        for (int i = 0; i < 12; ++i)
          acc[j][i] = fmaf(wv[j], xf[i], acc[j][i]);
    }
  }

  // bn1 stats: fp32 partials -> shfl over 32 lg lanes -> double atomics
  float s[8], q[8];
#pragma unroll
  for (int j = 0; j < 8; ++j) { s[j] = 0.f; q[j] = 0.f; }
  const int nv = L1 - (l0 + lb);  // valid positions this thread (may be <=0)
#pragma unroll
  for (int i = 0; i < 12; ++i) {
    if (i < nv) {
#pragma unroll
      for (int j = 0; j < 8; ++j) {
        s[j] += acc[j][i];
        q[j] += acc[j][i] * acc[j][i];
      }
    }
  }
#pragma unroll
  for (int m = 1; m < 32; m <<= 1) {
#pragma unroll
    for (int j = 0; j < 8; ++j) {
      s[j] += __shfl_xor(s[j], m, 64);
      q[j] += __shfl_xor(q[j], m, 64);
    }
  }
  if (lg == 0) {
#pragma unroll
    for (int j = 0; j < 8; ++j) {
      atomicAdd(&st[2 * (og * 8 + j)], (double)s[j]);
      atomicAdd(&st[2 * (og * 8 + j) + 1], (double)q[j]);
    }
  }

  // max3 pooling -> maxb[b][p][64]
  const int p0 = blockIdx.x * 128;
#pragma unroll
  for (int pi = 0; pi < 4; ++pi) {
    int p = p0 + lg * 4 + pi;
    if (p < P1) {
      float mv[8];
#pragma unroll
      for (int j = 0; j < 8; ++j)
        mv[j] = fmaxf(acc[j][3 * pi], fmaxf(acc[j][3 * pi + 1], acc[j][3 * pi + 2]));
      float* dst = maxb + ((size_t)b * P1 + p) * 64 + og * 8;
      *(float4*)dst = make_float4(mv[0], mv[1], mv[2], mv[3]);
      *(float4*)(dst + 4) = make_float4(mv[4], mv[5], mv[6], mv[7]);
    }
  }
}

// ---- apply bn1 sign to pooled maxes -> h1p [b][p][64] int8 ----
__global__ void k_pool1(const float* __restrict__ mb, int8_t* __restrict__ o,
                        const float* __restrict__ sc, const float* __restrict__ sh,
                        int total) {
  int i = blockIdx.x * 256 + threadIdx.x;
  if (i >= total) return;
  int ch = i & 63;
  o[i] = fsign(mb[i] * sc[ch] + sh[ch]);
}

// ---- finalize BN (double stats) -> scale/shift ----
__global__ void k_finalize_d(const double* __restrict__ st, const float* __restrict__ g,
                             const float* __restrict__ bb, float* __restrict__ sc,
                             float* __restrict__ sh, int C, double invN) {
  int c = blockIdx.x * blockDim.x + threadIdx.x;
  if (c >= C) return;
  double m = st[2 * c] * invN;
  double v = st[2 * c + 1] * invN - m * m;
  double s = (double)g[c] * rsqrt(v + 1e-5);
  sc[c] = (float)s;
  sh[c] = (float)((double)bb[c] - m * s);
}

// ---- finalize BN (int64 stats) ----
__global__ void k_finalize_ll(const ll* __restrict__ st, const float* __restrict__ g,
                              const float* __restrict__ bb, float* __restrict__ sc,
                              float* __restrict__ sh, int C, double invN) {
  int c = blockIdx.x * blockDim.x + threadIdx.x;
  if (c >= C) return;
  double m = (double)st[2 * c] * invN;
  double v = (double)st[2 * c + 1] * invN - m * m;
  double s = (double)g[c] * rsqrt(v + 1e-5);
  sc[c] = (float)s;
  sh[c] = (float)((double)bb[c] - m * s);
}

// ---- MFMA binarized conv, dilation 2 ----
// xT: [B][Lin][CIN] int8 (channel-last), wp: [41][COUT][CIN] int8,
// hT: [B][Lout][COUT] int16. Block = 4 waves; wave = 16 out-ch x 64 positions.
template <int CIN, int COUT>
__global__ __launch_bounds__(256) void k_bconv_mfma(const int8_t* __restrict__ xT,
                                                    const int8_t* __restrict__ wp,
                                                    short* __restrict__ hT,
                                                    int Lin, int Lout) {
  const int b = blockIdx.z;
  const int l0 = blockIdx.x * 64;
  const int ro = blockIdx.y * 64 + (threadIdx.x >> 6) * 16;  // 16-row group
  const int lane = threadIdx.x & 63;
  const int r16 = lane & 15;   // A-row / B-col / D-col within fragment
  const int kg = lane >> 4;    // k-group (8-byte sub-block)

  v4i acc[4] = {v4i{0,0,0,0}, v4i{0,0,0,0}, v4i{0,0,0,0}, v4i{0,0,0,0}};

  const int8_t* xb = xT + (size_t)b * Lin * CIN + (size_t)(l0 + r16) * CIN + kg * 8;
  const int8_t* wb = wp + (size_t)(ro + r16) * CIN + kg * 8;

  for (int t = 0; t < 41; ++t) {
#pragma unroll
    for (int cc = 0; cc < CIN / 32; ++cc) {
      const int cb = cc * 32;
      long long a = *(const long long*)(wb + (size_t)t * COUT * CIN + cb);
      const int8_t* bp = xb + (size_t)(2 * t) * CIN + cb;
#pragma unroll
      for (int u = 0; u < 4; ++u) {
        long long bf = *(const long long*)(bp + (size_t)(16 * u) * CIN);
        acc[u] = __builtin_amdgcn_mfma_i32_16x16x32_i8(a, bf, acc[u], 0, 0, 0);
      }
    }
  }
#pragma unroll
  for (int u = 0; u < 4; ++u) {
    int p = l0 + 16 * u + r16;
    if (p < Lout) {
      short4 v;
      v.x = (short)acc[u][0]; v.y = (short)acc[u][1];
      v.z = (short)acc[u][2]; v.w = (short)acc[u][3];
      *(short4*)(hT + ((size_t)b * Lout + p) * COUT + ro + kg * 4) = v;
    }
  }
}

// ---- per-channel sum/sumsq over hT [rows][C] int16 ----
template <int C>
__global__ __launch_bounds__(256) void k_stats16(const short* __restrict__ hT,
                                                 ull* __restrict__ st, int rows) {
  const int tid = threadIdx.x;
  const int c = tid % C;
  const int phase = tid / C;
  const int RP = 256 / C;
  int chunk = (rows + gridDim.x - 1) / gridDim.x;
  int r0 = blockIdx.x * chunk;
  int r1 = r0 + chunk; if (r1 > rows) r1 = rows;
  ll s = 0, q = 0;
  for (int r = r0 + phase; r < r1; r += RP) {
    int v = hT[(size_t)r * C + c];
    s += v; q += (ll)v * v;
  }
  __shared__ ll ss[256], qq[256];
  ss[tid] = s; qq[tid] = q;
  __syncthreads();
  for (int off = 128; off >= C; off >>= 1) {
    if (tid < off) { ss[tid] += ss[tid + off]; qq[tid] += qq[tid + off]; }
    __syncthreads();
  }
  if (tid < C) {
    atomicAdd(&st[2 * tid], (ull)ss[tid]);
    atomicAdd(&st[2 * tid + 1], (ull)qq[tid]);
  }
}

// ---- bn + htanh + maxpool3 + sign: hT [b][Lout][C] int16 -> xT [b][Lp][C] int8 ----
__global__ void k_pool(const short* __restrict__ hT, int8_t* __restrict__ o,
                       const float* __restrict__ sc, const float* __restrict__ sh,
                       int C, int Lout, int Lp, int total) {
  int i = blockIdx.x * 256 + threadIdx.x;
  if (i >= total) return;
  int c = i % C;
  int t = i / C;
  int pp = t % Lp;
  int b = t / Lp;
  const short* hp = hT + ((size_t)b * Lout + 3 * pp) * C + c;
  float s = sc[c], bb = sh[c];
  float y0 = (float)hp[0] * s + bb;
  float y1 = (float)hp[C] * s + bb;
  float y2 = (float)hp[2 * C] * s + bb;
  o[i] = fsign(fmaxf(y0, fmaxf(y1, y2)));
}

// ---- conv5 epilogue: hT5 [b][78][128] -> e1 [b][c*78+p] (reference flatten order) ----
__global__ void k_bn_sign_t(const short* __restrict__ hT, int8_t* __restrict__ e,
                            const float* __restrict__ sc, const float* __restrict__ sh) {
  int i = blockIdx.x * 256 + threadIdx.x;
  if (i >= BB * 128 * L5) return;
  int p = i % L5;
  int c = (i / L5) % 128;
  int b = i / (L5 * 128);
  float y = (float)hT[((size_t)b * L5 + p) * 128 + c] * sc[c] + sh[c];
  e[i] = fsign(y);
}

// ---- bn + sign for FC activations (layout [b][F]) ----
__global__ void k_bn_sign_fc(const int* __restrict__ h, int8_t* __restrict__ o,
                             const float* __restrict__ sc, const float* __restrict__ sh,
                             int F, int total) {
  int i = blockIdx.x * 256 + threadIdx.x;
  if (i >= total) return;
  int c = i % F;
  float y = (float)h[i] * sc[c] + sh[c];
  o[i] = fsign(y);
}

// ---- binarized FC: out[b][f] = sum_i e[b][i]*w[f][i] ----
template <int K>
__global__ __launch_bounds__(256) void k_fc(const int8_t* __restrict__ e,
                                            const int8_t* __restrict__ w,
                                            int* __restrict__ out, int F) {
  __shared__ int es[K / 4];
  const int b = blockIdx.y;
  const int* ep = (const int*)(e + (size_t)b * K);
  for (int i = threadIdx.x; i < K / 4; i += 256) es[i] = ep[i];
  __syncthreads();
  const int f = blockIdx.x * 256 + threadIdx.x;
  if (f >= F) return;
  const int* wp = (const int*)(w + (size_t)f * K);
  int acc = 0;
  for (int i = 0; i < K / 4; ++i) {
    int wd = wp[i], ed = es[i];
    acc += (int)(int8_t)(wd) * (int)(int8_t)(ed)
         + (int)(int8_t)(wd >> 8) * (int)(int8_t)(ed >> 8)
         + (int)(int8_t)(wd >> 16) * (int)(int8_t)(ed >> 16)
         + (int)(wd >> 24) * (int)(ed >> 24);
  }
  out[(size_t)b * F + f] = acc;
}

// ---- FC batchnorm stats over batch (N=64) -> scale/shift directly ----
__global__ void k_fcstats(const int* __restrict__ fc, const float* __restrict__ g,
                          const float* __restrict__ bb, float* __restrict__ sc,
                          float* __restrict__ sh, int F) {
  int f = blockIdx.x * blockDim.x + threadIdx.x;
  if (f >= F) return;
  double s = 0.0, q = 0.0;
  for (int b = 0; b < BB; ++b) {
    double v = (double)fc[(size_t)b * F + f];
    s += v; q += v * v;
  }
  double m = s / 64.0;
  double v = q / 64.0 - m * m;
  double scd = (double)g[f] * rsqrt(v + 1e-5);
  sc[f] = (float)scd;
  sh[f] = (float)((double)bb[f] - m * scd);
}

// ---- bn7 + log_softmax, one block per batch row ----
__global__ __launch_bounds__(256) void k_lsm(const int* __restrict__ fc,
                                             const float* __restrict__ sc,
                                             const float* __restrict__ sh,
                                             float* __restrict__ out) {
  __shared__ float y[1000];
  __shared__ float red[256];
  const int b = blockIdx.x;
  float lm = -3.4e38f;
  for (int j = threadIdx.x; j < 1000; j += 256) {
    float v = (float)fc[b * 1000 + j] * sc[j] + sh[j];
    y[j] = v;
    lm = fmaxf(lm, v);
  }
  red[threadIdx.x] = lm;
  __syncthreads();
  for (int off = 128; off; off >>= 1) {
    if (threadIdx.x < off) red[threadIdx.x] = fmaxf(red[threadIdx.x], red[threadIdx.x + off]);
    __syncthreads();
  }
  const float M = red[0];
  __syncthreads();
  float ls = 0.f;
  for (int j = threadIdx.x; j < 1000; j += 256) ls += expf(y[j] - M);
  red[threadIdx.x] = ls;
  __syncthreads();
  for (int off = 128; off; off >>= 1) {
    if (threadIdx.x < off) red[threadIdx.x] += red[threadIdx.x + off];
    __syncthreads();
  }
  const float L = M + logf(red[0]);
  for (int j = threadIdx.x; j < 1000; j += 256) out[b * 1000 + j] = y[j] - L;
}

extern "C" void kernel_launch(void* const* d_in, const int* in_sizes, int n_in,
                              void* d_out, int out_size, void* d_ws, size_t ws_size,
                              hipStream_t stream) {
  if (ws_size < WS_NEED) return;
  char* ws = (char*)d_ws;

  const float* x   = (const float*)d_in[0];
  const float* g0  = (const float*)d_in[1];
  const float* w1  = (const float*)d_in[3];
  const float* g1  = (const float*)d_in[5];
  const float* b1  = (const float*)d_in[6];
  const float* w2  = (const float*)d_in[7];
  const float* g2  = (const float*)d_in[9];
  const float* b2  = (const float*)d_in[10];
  const float* w3  = (const float*)d_in[11];
  const float* g3  = (const float*)d_in[13];
  const float* b3  = (const float*)d_in[14];
  const float* w4  = (const float*)d_in[15];
  const float* g4  = (const float*)d_in[17];
  const float* b4  = (const float*)d_in[18];
  const float* w5  = (const float*)d_in[19];
  const float* g5  = (const float*)d_in[21];
  const float* b5  = (const float*)d_in[22];
  const float* fw1 = (const float*)d_in[23];
  const float* g6  = (const float*)d_in[25];
  const float* b6  = (const float*)d_in[26];
  const float* fw2 = (const float*)d_in[27];
  const float* g7  = (const float*)d_in[29];
  const float* b7  = (const float*)d_in[30];
  float* out = (float*)d_out;

  double* st0 = (double*)(ws + SO_BN0);
  double* st1 = (double*)(ws + SO_BN1);
  ull* st2 = (ull*)(ws + SO_BN2);
  ull* st3 = (ull*)(ws + SO_BN3);
  ull* st4 = (ull*)(ws + SO_BN4);
  ull* st5 = (ull*)(ws + SO_BN5);
  float* sc1 = (float*)(ws + SO_SC1); float* sh1 = (float*)(ws + SO_SH1);
  float* sc2 = (float*)(ws + SO_SC2); float* sh2 = (float*)(ws + SO_SH2);
  float* sc3 = (float*)(ws + SO_SC3); float* sh3 = (float*)(ws + SO_SH3);
  float* sc4 = (float*)(ws + SO_SC4); float* sh4 = (float*)(ws + SO_SH4);
  float* sc5 = (float*)(ws + SO_SC5); float* sh5 = (float*)(ws + SO_SH5);
  float* sc6 = (float*)(ws + SO_SC6); float* sh6 = (float*)(ws + SO_SH6);
  float* sc7 = (float*)(ws + SO_SC7); float* sh7 = (float*)(ws + SO_SH7);

  float* w1T   = (float*)(ws + OFF_W1T);
  int8_t* h1p  = (int8_t*)(ws + OFF_H1P);   // [64][P1][64]
  float* maxb  = (float*)(ws + OFF_MAXB);   // [64][P1][64]

  int8_t* wp2 = (int8_t*)(ws + OFF_WP2);
  int8_t* wp3 = (int8_t*)(ws + OFF_WP3);
  int8_t* wp4 = (int8_t*)(ws + OFF_WP4);
  int8_t* wp5 = (int8_t*)(ws + OFF_WP5);
  int8_t* sfw1 = (int8_t*)(ws + OFF_SFW1);
  int8_t* sfw2 = (int8_t*)(ws + OFF_SFW2);

  short*  h2  = (short*)(ws + OFF_X);    // [64][L2][64]
  int8_t* h2p = (int8_t*)(ws + OFF_Y);   // [64][P2][64]
  short*  h3  = (short*)(ws + OFF_X);    // [64][L3][128]
  int8_t* h3p = (int8_t*)(ws + OFF_Y);   // [64][P3][128]
  short*  h4  = (short*)(ws + OFF_X);    // [64][L4][128]
  int8_t* h4p = (int8_t*)(ws + OFF_Y);   // [64][P4][128]
  short*  h5  = (short*)(ws + OFF_X);    // [64][L5][128]
  int8_t* e1  = (int8_t*)(ws + OFF_Y);   // [64][EMB]
  int*    fc1o = (int*)(ws + OFF_X);
  int8_t* e2  = (int8_t*)(ws + OFF_Y);
  int*    fc2o = (int*)(ws + OFF_X);

  hipMemsetAsync(ws, 0, STATS_BYTES, stream);

  // ---- conv1 phase ----
  k_bn0_stats<<<192, 256, 0, stream>>>(x, st0);
  k_prep_w1T<<<1, 256, 0, stream>>>(w1, g0, st0, w1T);
  k_conv1_fused<<<dim3(42, 64), 256, 0, stream>>>(x, w1T, st1, maxb);
  k_finalize_d<<<1, 64, 0, stream>>>(st1, g1, b1, sc1, sh1, 64, 1.0 / ((double)BB * L1));
  k_pool1<<<(BB * P1 * 64 + 255) / 256, 256, 0, stream>>>(maxb, h1p, sc1, sh1, BB * P1 * 64);

  // ---- pack binarized weights (after pool1: these alias the maxbuf span) ----
  k_prep_wconv<<<656, 256, 0, stream>>>(w2, wp2, 64, 64);
  k_prep_wconv<<<1024, 256, 0, stream>>>(w3, wp3, 128, 64);
  k_prep_wconv<<<1024, 256, 0, stream>>>(w4, wp4, 128, 128);
  k_prep_wconv<<<1024, 256, 0, stream>>>(w5, wp5, 128, 128);
  k_sign8<<<2048, 256, 0, stream>>>(fw1, sfw1, 2048 * EMB);
  k_sign8<<<1024, 256, 0, stream>>>(fw2, sfw2, 1000 * 2048);

  // conv2 (MFMA)
  k_bconv_mfma<64, 64><<<dim3(82, 1, 64), 256, 0, stream>>>(h1p, wp2, h2, P1, L2);
  k_stats16<64><<<256, 256, 0, stream>>>(h2, st2, BB * L2);
  k_finalize_ll<<<1, 64, 0, stream>>>((const ll*)st2, g2, b2, sc2, sh2, 64, 1.0 / ((double)BB * L2));
  k_pool<<<(BB * 64 * P2 + 255) / 256, 256, 0, stream>>>(h2, h2p, sc2, sh2, 64, L2, P2, BB * 64 * P2);

  // conv3
  k_bconv_mfma<64, 128><<<dim3(26, 2, 64), 256, 0, stream>>>(h2p, wp3, h3, P2, L3);
  k_stats16<128><<<256, 256, 0, stream>>>(h3, st3, BB * L3);
  k_finalize_ll<<<1, 128, 0, stream>>>((const ll*)st3, g3, b3, sc3, sh3, 128, 1.0 / ((double)BB * L3));
  k_pool<<<(BB * 128 * P3 + 255) / 256, 256, 0, stream>>>(h3, h3p, sc3, sh3, 128, L3, P3, BB * 128 * P3);

  // conv4
  k_bconv_mfma<128, 128><<<dim3(8, 2, 64), 256, 0, stream>>>(h3p, wp4, h4, P3, L4);
  k_stats16<128><<<256, 256, 0, stream>>>(h4, st4, BB * L4);
  k_finalize_ll<<<1, 128, 0, stream>>>((const ll*)st4, g4, b4, sc4, sh4, 128, 1.0 / ((double)BB * L4));
  k_pool<<<(BB * 128 * P4 + 255) / 256, 256, 0, stream>>>(h4, h4p, sc4, sh4, 128, L4, P4, BB * 128 * P4);

  // conv5 (no pool; bn5+htanh+sign -> e1, re-transposed to [b][c*78+p])
  k_bconv_mfma<128, 128><<<dim3(2, 2, 64), 256, 0, stream>>>(h4p, wp5, h5, P4, L5);
  k_stats16<128><<<256, 256, 0, stream>>>(h5, st5, BB * L5);
  k_finalize_ll<<<1, 128, 0, stream>>>((const ll*)st5, g5, b5, sc5, sh5, 128, 1.0 / ((double)BB * L5));
  k_bn_sign_t<<<(BB * EMB + 255) / 256, 256, 0, stream>>>(h5, e1, sc5, sh5);

  // fc1 -> bn6 -> sign
  k_fc<EMB><<<dim3(8, BB), 256, 0, stream>>>(e1, sfw1, fc1o, 2048);
  k_fcstats<<<8, 256, 0, stream>>>(fc1o, g6, b6, sc6, sh6, 2048);
  k_bn_sign_fc<<<(BB * 2048 + 255) / 256, 256, 0, stream>>>(fc1o, e2, sc6, sh6, 2048, BB * 2048);

  // fc2 -> bn7 -> log_softmax
  k_fc<2048><<<dim3(4, BB), 256, 0, stream>>>(e2, sfw2, fc2o, 1000);
  k_fcstats<<<4, 256, 0, stream>>>(fc2o, g7, b7, sc7, sh7, 1000);
  k_lsm<<<64, 256, 0, stream>>>(fc2o, sc7, sh7, out);
}

// Round 5
// 2464.142 us; speedup vs baseline: 8.9443x; 1.0040x over previous
//
#include <hip/hip_runtime.h>
#include <stdint.h>

typedef long long ll;
typedef unsigned long long ull;
typedef int v4i __attribute__((ext_vector_type(4)));

// ---- problem dims ----
#define BB 64
#define L0 15958
#define L1 15918
#define P1 5306
#define L2 5226
#define P2 1742
#define L3 1662
#define P3 554
#define L4 474
#define P4 158
#define L5 78
#define EMB 9984

// ---- ws layout (bytes) ----
// stats / scale-shift block (zeroed each launch)
#define SO_BN0 0
#define SO_BN1 64
#define SO_BN2 1088
#define SO_BN3 2112
#define SO_BN4 4160
#define SO_BN5 6208
#define SO_SC1 8256
#define SO_SH1 8512
#define SO_SC2 8768
#define SO_SH2 9024
#define SO_SC3 9280
#define SO_SH3 9792
#define SO_SC4 10304
#define SO_SH4 10816
#define SO_SC5 11328
#define SO_SH5 11840
#define SO_SC6 12352
#define SO_SH6 20544
#define SO_SC7 28736
#define SO_SH7 32736
#define STATS_BYTES 65536ull

// persistent through conv1 phase
#define OFF_W1T  65536ull        // 123*64*4 = 31488
#define OFF_H1P  98304ull        // 64*P1*64 = 21,733,376
#define OFF_MAXB 21831680ull     // 64*P1*64*4 = 86,933,504 (ends 108,765,184)

// phase-2 regions (alias the maxbuf span; used only after k_pool1)
#define OFF_WP2  21831680ull     // 41*64*64   = 167,936
#define OFF_WP3  21999616ull     // 41*128*64  = 335,872
#define OFF_WP4  22335488ull     // 41*128*128 = 671,744
#define OFF_WP5  23007232ull     // 671,744
#define OFF_SFW1 23678976ull     // 2048*9984  = 20,447,232
#define OFF_SFW2 44126208ull     // 1000*2048  = 2,048,000
#define OFF_X    46174208ull     // big ping (<= 42,811,392)
#define OFF_Y    88985600ull     // small pong (<= 7,131,136)
#define WS_NEED  109051904ull

__device__ __forceinline__ int8_t fsign(float v) {
  return (v > 0.f) ? (int8_t)1 : ((v < 0.f) ? (int8_t)(-1) : (int8_t)0);
}

// ---- binarize a float tensor to int8 sign (layout-preserving) ----
__global__ void k_sign8(const float* __restrict__ w, int8_t* __restrict__ o, int n) {
  int stride = gridDim.x * blockDim.x;
  for (int i = blockIdx.x * blockDim.x + threadIdx.x; i < n; i += stride) {
    float v = w[i];
    o[i] = (v > 0.f) ? 1 : ((v < 0.f) ? -1 : 0);
  }
}

// ---- pack conv weights: w[o][c][t] fp32 -> sign int8 at [t][o][c] ----
__global__ void k_prep_wconv(const float* __restrict__ w, int8_t* __restrict__ o,
                             int COUT, int CIN) {
  int n = COUT * CIN * 41;
  int stride = gridDim.x * blockDim.x;
  for (int i = blockIdx.x * blockDim.x + threadIdx.x; i < n; i += stride) {
    int oc = i / (CIN * 41);
    int r = i - oc * CIN * 41;
    int c = r / 41;
    int t = r - c * 41;
    float v = w[i];
    int8_t s = (v > 0.f) ? 1 : ((v < 0.f) ? -1 : 0);
    o[((size_t)t * COUT + oc) * CIN + c] = s;
  }
}

// ---- bn0 stats: per-channel (3) sum/sumsq over (B, L0) ----
__global__ __launch_bounds__(256) void k_bn0_stats(const float* __restrict__ x,
                                                   double* __restrict__ st) {
  const int r = blockIdx.x;            // b*3 + c, 0..191
  const int c = r % 3;
  const float* p = x + (size_t)r * L0;
  double s = 0.0, s2 = 0.0;
  for (int i = threadIdx.x; i < L0; i += 256) {
    double v = (double)p[i];
    s += v; s2 += v * v;
  }
  __shared__ double rs[256], rq[256];
  rs[threadIdx.x] = s; rq[threadIdx.x] = s2;
  __syncthreads();
  for (int off = 128; off; off >>= 1) {
    if (threadIdx.x < off) {
      rs[threadIdx.x] += rs[threadIdx.x + off];
      rq[threadIdx.x] += rq[threadIdx.x + off];
    }
    __syncthreads();
  }
  if (threadIdx.x == 0) {
    atomicAdd(&st[2 * c], rs[0]);
    atomicAdd(&st[2 * c + 1], rq[0]);
  }
}

// ---- fold bn0 scale into sign(w1), TRANSPOSED: wT[(c*41+k)*64 + o] = sign*a_c ----
__global__ void k_prep_w1T(const float* __restrict__ w1, const float* __restrict__ g0,
                           const double* __restrict__ st0, float* __restrict__ wT) {
  __shared__ float a[3];
  if (threadIdx.x < 3) {
    const double N = (double)BB * (double)L0;
    double m = st0[2 * threadIdx.x] / N;
    double v = st0[2 * threadIdx.x + 1] / N - m * m;
    a[threadIdx.x] = (float)((double)g0[threadIdx.x] * rsqrt(v + 1e-5));
  }
  __syncthreads();
  for (int i = threadIdx.x; i < 64 * 123; i += blockDim.x) {
    int o = i / 123;
    int r = i - o * 123;
    int c = r / 41;
    float w = w1[i];
    float s = (w > 0.f) ? 1.f : ((w < 0.f) ? -1.f : 0.f);
    wT[r * 64 + o] = s * a[c];
  }
}

// ---- fused conv1 v3: weights in LDS (broadcast reads), x streamed from global/L1 ----
// Block: 256 threads = 8 og * 32 lg; tile = 64 out-ch x 384 positions.
// Thread: 8 out-ch (og*8..+7) x 12 positions (lg*12..+11) = 4 aligned pools.
__global__ __launch_bounds__(256) void k_conv1_fused(const float* __restrict__ x,
                                                     const float* __restrict__ wT,
                                                     double* __restrict__ st,
                                                     float* __restrict__ maxb) {
  __shared__ float wl[123 * 64];
  const int b = blockIdx.y;
  const int l0 = blockIdx.x * 384;
  for (int i = threadIdx.x; i < 123 * 64; i += 256) wl[i] = wT[i];
  __syncthreads();

  const int og = threadIdx.x >> 5;   // 0..7 -> out-ch og*8..+7
  const int lg = threadIdx.x & 31;   // 0..31 -> pos lg*12..+11
  const int lb = lg * 12;
  const bool safe = (l0 + 424 <= L0);  // block-uniform fast path

  float acc[8][12];
#pragma unroll
  for (int j = 0; j < 8; ++j)
#pragma unroll
    for (int i = 0; i < 12; ++i) acc[j][i] = 0.f;

  const float4* wl4 = (const float4*)wl;
  for (int c = 0; c < 3; ++c) {
    const float* xr = x + ((size_t)b * 3 + c) * L0 + l0 + lb;  // even offset
    const int wbase = c * 41;
    for (int g = 0; g < 10; ++g) {
      float xf[16];
      if (safe) {
        const float2* xr2 = (const float2*)(xr + 4 * g);  // 8B-aligned always
#pragma unroll
        for (int h = 0; h < 8; ++h) {
          float2 v = xr2[h];
          xf[2 * h] = v.x; xf[2 * h + 1] = v.y;
        }
      } else {
#pragma unroll
        for (int t = 0; t < 16; ++t) {
          int gl = l0 + lb + 4 * g + t;
          xf[t] = (gl < L0) ? xr[4 * g + t] : 0.f;
        }
      }
#pragma unroll
      for (int k4 = 0; k4 < 4; ++k4) {
        const int widx = ((wbase + 4 * g + k4) * 64 + og * 8) >> 2;
        float4 wa = wl4[widx];       // wave-uniform per og -> LDS broadcast
        float4 wb = wl4[widx + 1];
        float wv[8] = {wa.x, wa.y, wa.z, wa.w, wb.x, wb.y, wb.z, wb.w};
#pragma unroll
        for (int j = 0; j < 8; ++j)
#pragma unroll
          for (int i = 0; i < 12; ++i)
            acc[j][i] = fmaf(wv[j], xf[k4 + i], acc[j][i]);
      }
    }
    {  // kk = 40 epilogue
      float xf[12];
      if (safe) {
        const float2* xr2 = (const float2*)(xr + 40);
#pragma unroll
        for (int h = 0; h < 6; ++h) {
          float2 v = xr2[h];
          xf[2 * h] = v.x; xf[2 * h + 1] = v.y;
        }
      } else {
#pragma unroll
        for (int t = 0; t < 12; ++t) {
          int gl = l0 + lb + 40 + t;
          xf[t] = (gl < L0) ? xr[40 + t] : 0.f;
        }
      }
      const int widx = ((wbase + 40) * 64 + og * 8) >> 2;
      float4 wa = wl4[widx];
      float4 wb = wl4[widx + 1];
      float wv[8] = {wa.x, wa.y, wa.z, wa.w, wb.x, wb.y, wb.z, wb.w};
#pragma unroll
      for (int j = 0; j < 8; ++j)
#pragma unroll
        for (int i = 0; i < 12; ++i)
          acc[j][i] = fmaf(wv[j], xf[i], acc[j][i]);
    }
  }

  // bn1 stats: fp32 partials -> shfl over 32 lg lanes -> double atomics
  float s[8], q[8];
#pragma unroll
  for (int j = 0; j < 8; ++j) { s[j] = 0.f; q[j] = 0.f; }
  const int nv = L1 - (l0 + lb);  // valid positions this thread (may be <=0)
#pragma unroll
  for (int i = 0; i < 12; ++i) {
    if (i < nv) {
#pragma unroll
      for (int j = 0; j < 8; ++j) {
        s[j] += acc[j][i];
        q[j] += acc[j][i] * acc[j][i];
      }
    }
  }
#pragma unroll
  for (int m = 1; m < 32; m <<= 1) {
#pragma unroll
    for (int j = 0; j < 8; ++j) {
      s[j] += __shfl_xor(s[j], m, 64);
      q[j] += __shfl_xor(q[j], m, 64);
    }
  }
  if (lg == 0) {
#pragma unroll
    for (int j = 0; j < 8; ++j) {
      atomicAdd(&st[2 * (og * 8 + j)], (double)s[j]);
      atomicAdd(&st[2 * (og * 8 + j) + 1], (double)q[j]);
    }
  }

  // max3 pooling -> maxb[b][p][64]
  const int p0 = blockIdx.x * 128;
#pragma unroll
  for (int pi = 0; pi < 4; ++pi) {
    int p = p0 + lg * 4 + pi;
    if (p < P1) {
      float mv[8];
#pragma unroll
      for (int j = 0; j < 8; ++j)
        mv[j] = fmaxf(acc[j][3 * pi], fmaxf(acc[j][3 * pi + 1], acc[j][3 * pi + 2]));
      float* dst = maxb + ((size_t)b * P1 + p) * 64 + og * 8;
      *(float4*)dst = make_float4(mv[0], mv[1], mv[2], mv[3]);
      *(float4*)(dst + 4) = make_float4(mv[4], mv[5], mv[6], mv[7]);
    }
  }
}

// ---- apply bn1 sign to pooled maxes -> h1p [b][p][64] int8 ----
__global__ void k_pool1(const float* __restrict__ mb, int8_t* __restrict__ o,
                        const float* __restrict__ sc, const float* __restrict__ sh,
                        int total) {
  int i = blockIdx.x * 256 + threadIdx.x;
  if (i >= total) return;
  int ch = i & 63;
  o[i] = fsign(mb[i] * sc[ch] + sh[ch]);
}

// ---- finalize BN (double stats) -> scale/shift ----
__global__ void k_finalize_d(const double* __restrict__ st, const float* __restrict__ g,
                             const float* __restrict__ bb, float* __restrict__ sc,
                             float* __restrict__ sh, int C, double invN) {
  int c = blockIdx.x * blockDim.x + threadIdx.x;
  if (c >= C) return;
  double m = st[2 * c] * invN;
  double v = st[2 * c + 1] * invN - m * m;
  double s = (double)g[c] * rsqrt(v + 1e-5);
  sc[c] = (float)s;
  sh[c] = (float)((double)bb[c] - m * s);
}

// ---- finalize BN (int64 stats) ----
__global__ void k_finalize_ll(const ll* __restrict__ st, const float* __restrict__ g,
                              const float* __restrict__ bb, float* __restrict__ sc,
                              float* __restrict__ sh, int C, double invN) {
  int c = blockIdx.x * blockDim.x + threadIdx.x;
  if (c >= C) return;
  double m = (double)st[2 * c] * invN;
  double v = (double)st[2 * c + 1] * invN - m * m;
  double s = (double)g[c] * rsqrt(v + 1e-5);
  sc[c] = (float)s;
  sh[c] = (float)((double)bb[c] - m * s);
}

// ---- MFMA binarized conv, dilation 2 ----
// xT: [B][Lin][CIN] int8 (channel-last), wp: [41][COUT][CIN] int8,
// hT: [B][Lout][COUT] int16. Block = 4 waves; wave = 16 out-ch x 64 positions.
template <int CIN, int COUT>
__global__ __launch_bounds__(256) void k_bconv_mfma(const int8_t* __restrict__ xT,
                                                    const int8_t* __restrict__ wp,
                                                    short* __restrict__ hT,
                                                    int Lin, int Lout) {
  const int b = blockIdx.z;
  const int l0 = blockIdx.x * 64;
  const int ro = blockIdx.y * 64 + (threadIdx.x >> 6) * 16;  // 16-row group
  const int lane = threadIdx.x & 63;
  const int r16 = lane & 15;   // A-row / B-col / D-col within fragment
  const int kg = lane >> 4;    // k-group (8-byte sub-block)

  v4i acc[4] = {v4i{0,0,0,0}, v4i{0,0,0,0}, v4i{0,0,0,0}, v4i{0,0,0,0}};

  const int8_t* xb = xT + (size_t)b * Lin * CIN + (size_t)(l0 + r16) * CIN + kg * 8;
  const int8_t* wb = wp + (size_t)(ro + r16) * CIN + kg * 8;

  for (int t = 0; t < 41; ++t) {
#pragma unroll
    for (int cc = 0; cc < CIN / 32; ++cc) {
      const int cb = cc * 32;
      long long a = *(const long long*)(wb + (size_t)t * COUT * CIN + cb);
      const int8_t* bp = xb + (size_t)(2 * t) * CIN + cb;
#pragma unroll
      for (int u = 0; u < 4; ++u) {
        long long bf = *(const long long*)(bp + (size_t)(16 * u) * CIN);
        acc[u] = __builtin_amdgcn_mfma_i32_16x16x32_i8(a, bf, acc[u], 0, 0, 0);
      }
    }
  }
#pragma unroll
  for (int u = 0; u < 4; ++u) {
    int p = l0 + 16 * u + r16;
    if (p < Lout) {
      short4 v;
      v.x = (short)acc[u][0]; v.y = (short)acc[u][1];
      v.z = (short)acc[u][2]; v.w = (short)acc[u][3];
      *(short4*)(hT + ((size_t)b * Lout + p) * COUT + ro + kg * 4) = v;
    }
  }
}

// ---- per-channel sum/sumsq over hT [rows][C] int16 ----
template <int C>
__global__ __launch_bounds__(256) void k_stats16(const short* __restrict__ hT,
                                                 ull* __restrict__ st, int rows) {
  const int tid = threadIdx.x;
  const int c = tid % C;
  const int phase = tid / C;
  const int RP = 256 / C;
  int chunk = (rows + gridDim.x - 1) / gridDim.x;
  int r0 = blockIdx.x * chunk;
  int r1 = r0 + chunk; if (r1 > rows) r1 = rows;
  ll s = 0, q = 0;
  for (int r = r0 + phase; r < r1; r += RP) {
    int v = hT[(size_t)r * C + c];
    s += v; q += (ll)v * v;
  }
  __shared__ ll ss[256], qq[256];
  ss[tid] = s; qq[tid] = q;
  __syncthreads();
  for (int off = 128; off >= C; off >>= 1) {
    if (tid < off) { ss[tid] += ss[tid + off]; qq[tid] += qq[tid + off]; }
    __syncthreads();
  }
  if (tid < C) {
    atomicAdd(&st[2 * tid], (ull)ss[tid]);
    atomicAdd(&st[2 * tid + 1], (ull)qq[tid]);
  }
}

// ---- bn + htanh + maxpool3 + sign: hT [b][Lout][C] int16 -> xT [b][Lp][C] int8 ----
__global__ void k_pool(const short* __restrict__ hT, int8_t* __restrict__ o,
                       const float* __restrict__ sc, const float* __restrict__ sh,
                       int C, int Lout, int Lp, int total) {
  int i = blockIdx.x * 256 + threadIdx.x;
  if (i >= total) return;
  int c = i % C;
  int t = i / C;
  int pp = t % Lp;
  int b = t / Lp;
  const short* hp = hT + ((size_t)b * Lout + 3 * pp) * C + c;
  float s = sc[c], bb = sh[c];
  float y0 = (float)hp[0] * s + bb;
  float y1 = (float)hp[C] * s + bb;
  float y2 = (float)hp[2 * C] * s + bb;
  o[i] = fsign(fmaxf(y0, fmaxf(y1, y2)));
}

// ---- conv5 epilogue: hT5 [b][78][128] -> e1 [b][c*78+p] (reference flatten order) ----
__global__ void k_bn_sign_t(const short* __restrict__ hT, int8_t* __restrict__ e,
                            const float* __restrict__ sc, const float* __restrict__ sh) {
  int i = blockIdx.x * 256 + threadIdx.x;
  if (i >= BB * 128 * L5) return;
  int p = i % L5;
  int c = (i / L5) % 128;
  int b = i / (L5 * 128);
  float y = (float)hT[((size_t)b * L5 + p) * 128 + c] * sc[c] + sh[c];
  e[i] = fsign(y);
}

// ---- bn + sign for FC activations (layout [b][F]) ----
__global__ void k_bn_sign_fc(const int* __restrict__ h, int8_t* __restrict__ o,
                             const float* __restrict__ sc, const float* __restrict__ sh,
                             int F, int total) {
  int i = blockIdx.x * 256 + threadIdx.x;
  if (i >= total) return;
  int c = i % F;
  float y = (float)h[i] * sc[c] + sh[c];
  o[i] = fsign(y);
}

// ---- binarized FC: out[b][f] = sum_i e[b][i]*w[f][i] ----
template <int K>
__global__ __launch_bounds__(256) void k_fc(const int8_t* __restrict__ e,
                                            const int8_t* __restrict__ w,
                                            int* __restrict__ out, int F) {
  __shared__ int es[K / 4];
  const int b = blockIdx.y;
  const int* ep = (const int*)(e + (size_t)b * K);
  for (int i = threadIdx.x; i < K / 4; i += 256) es[i] = ep[i];
  __syncthreads();
  const int f = blockIdx.x * 256 + threadIdx.x;
  if (f >= F) return;
  const int* wp = (const int*)(w + (size_t)f * K);
  int acc = 0;
  for (int i = 0; i < K / 4; ++i) {
    int wd = wp[i], ed = es[i];
    acc += (int)(int8_t)(wd) * (int)(int8_t)(ed)
         + (int)(int8_t)(wd >> 8) * (int)(int8_t)(ed >> 8)
         + (int)(int8_t)(wd >> 16) * (int)(int8_t)(ed >> 16)
         + (int)(wd >> 24) * (int)(ed >> 24);
  }
  out[(size_t)b * F + f] = acc;
}

// ---- FC batchnorm stats over batch (N=64) -> scale/shift directly ----
__global__ void k_fcstats(const int* __restrict__ fc, const float* __restrict__ g,
                          const float* __restrict__ bb, float* __restrict__ sc,
                          float* __restrict__ sh, int F) {
  int f = blockIdx.x * blockDim.x + threadIdx.x;
  if (f >= F) return;
  double s = 0.0, q = 0.0;
  for (int b = 0; b < BB; ++b) {
    double v = (double)fc[(size_t)b * F + f];
    s += v; q += v * v;
  }
  double m = s / 64.0;
  double v = q / 64.0 - m * m;
  double scd = (double)g[f] * rsqrt(v + 1e-5);
  sc[f] = (float)scd;
  sh[f] = (float)((double)bb[f] - m * scd);
}

// ---- bn7 + log_softmax, one block per batch row ----
__global__ __launch_bounds__(256) void k_lsm(const int* __restrict__ fc,
                                             const float* __restrict__ sc,
                                             const float* __restrict__ sh,
                                             float* __restrict__ out) {
  __shared__ float y[1000];
  __shared__ float red[256];
  const int b = blockIdx.x;
  float lm = -3.4e38f;
  for (int j = threadIdx.x; j < 1000; j += 256) {
    float v = (float)fc[b * 1000 + j] * sc[j] + sh[j];
    y[j] = v;
    lm = fmaxf(lm, v);
  }
  red[threadIdx.x] = lm;
  __syncthreads();
  for (int off = 128; off; off >>= 1) {
    if (threadIdx.x < off) red[threadIdx.x] = fmaxf(red[threadIdx.x], red[threadIdx.x + off]);
    __syncthreads();
  }
  const float M = red[0];
  __syncthreads();
  float ls = 0.f;
  for (int j = threadIdx.x; j < 1000; j += 256) ls += expf(y[j] - M);
  red[threadIdx.x] = ls;
  __syncthreads();
  for (int off = 128; off; off >>= 1) {
    if (threadIdx.x < off) red[threadIdx.x] += red[threadIdx.x + off];
    __syncthreads();
  }
  const float L = M + logf(red[0]);
  for (int j = threadIdx.x; j < 1000; j += 256) out[b * 1000 + j] = y[j] - L;
}

extern "C" void kernel_launch(void* const* d_in, const int* in_sizes, int n_in,
                              void* d_out, int out_size, void* d_ws, size_t ws_size,
                              hipStream_t stream) {
  if (ws_size < WS_NEED) return;
  char* ws = (char*)d_ws;

  const float* x   = (const float*)d_in[0];
  const float* g0  = (const float*)d_in[1];
  const float* w1  = (const float*)d_in[3];
  const float* g1  = (const float*)d_in[5];
  const float* b1  = (const float*)d_in[6];
  const float* w2  = (const float*)d_in[7];
  const float* g2  = (const float*)d_in[9];
  const float* b2  = (const float*)d_in[10];
  const float* w3  = (const float*)d_in[11];
  const float* g3  = (const float*)d_in[13];
  const float* b3  = (const float*)d_in[14];
  const float* w4  = (const float*)d_in[15];
  const float* g4  = (const float*)d_in[17];
  const float* b4  = (const float*)d_in[18];
  const float* w5  = (const float*)d_in[19];
  const float* g5  = (const float*)d_in[21];
  const float* b5  = (const float*)d_in[22];
  const float* fw1 = (const float*)d_in[23];
  const float* g6  = (const float*)d_in[25];
  const float* b6  = (const float*)d_in[26];
  const float* fw2 = (const float*)d_in[27];
  const float* g7  = (const float*)d_in[29];
  const float* b7  = (const float*)d_in[30];
  float* out = (float*)d_out;

  double* st0 = (double*)(ws + SO_BN0);
  double* st1 = (double*)(ws + SO_BN1);
  ull* st2 = (ull*)(ws + SO_BN2);
  ull* st3 = (ull*)(ws + SO_BN3);
  ull* st4 = (ull*)(ws + SO_BN4);
  ull* st5 = (ull*)(ws + SO_BN5);
  float* sc1 = (float*)(ws + SO_SC1); float* sh1 = (float*)(ws + SO_SH1);
  float* sc2 = (float*)(ws + SO_SC2); float* sh2 = (float*)(ws + SO_SH2);
  float* sc3 = (float*)(ws + SO_SC3); float* sh3 = (float*)(ws + SO_SH3);
  float* sc4 = (float*)(ws + SO_SC4); float* sh4 = (float*)(ws + SO_SH4);
  float* sc5 = (float*)(ws + SO_SC5); float* sh5 = (float*)(ws + SO_SH5);
  float* sc6 = (float*)(ws + SO_SC6); float* sh6 = (float*)(ws + SO_SH6);
  float* sc7 = (float*)(ws + SO_SC7); float* sh7 = (float*)(ws + SO_SH7);

  float* w1T   = (float*)(ws + OFF_W1T);
  int8_t* h1p  = (int8_t*)(ws + OFF_H1P);   // [64][P1][64]
  float* maxb  = (float*)(ws + OFF_MAXB);   // [64][P1][64]

  int8_t* wp2 = (int8_t*)(ws + OFF_WP2);
  int8_t* wp3 = (int8_t*)(ws + OFF_WP3);
  int8_t* wp4 = (int8_t*)(ws + OFF_WP4);
  int8_t* wp5 = (int8_t*)(ws + OFF_WP5);
  int8_t* sfw1 = (int8_t*)(ws + OFF_SFW1);
  int8_t* sfw2 = (int8_t*)(ws + OFF_SFW2);

  short*  h2  = (short*)(ws + OFF_X);    // [64][L2][64]
  int8_t* h2p = (int8_t*)(ws + OFF_Y);   // [64][P2][64]
  short*  h3  = (short*)(ws + OFF_X);    // [64][L3][128]
  int8_t* h3p = (int8_t*)(ws + OFF_Y);   // [64][P3][128]
  short*  h4  = (short*)(ws + OFF_X);    // [64][L4][128]
  int8_t* h4p = (int8_t*)(ws + OFF_Y);   // [64][P4][128]
  short*  h5  = (short*)(ws + OFF_X);    // [64][L5][128]
  int8_t* e1  = (int8_t*)(ws + OFF_Y);   // [64][EMB]
  int*    fc1o = (int*)(ws + OFF_X);
  int8_t* e2  = (int8_t*)(ws + OFF_Y);
  int*    fc2o = (int*)(ws + OFF_X);

  hipMemsetAsync(ws, 0, STATS_BYTES, stream);

  // ---- conv1 phase ----
  k_bn0_stats<<<192, 256, 0, stream>>>(x, st0);
  k_prep_w1T<<<1, 256, 0, stream>>>(w1, g0, st0, w1T);
  k_conv1_fused<<<dim3(42, 64), 256, 0, stream>>>(x, w1T, st1, maxb);
  k_finalize_d<<<1, 64, 0, stream>>>(st1, g1, b1, sc1, sh1, 64, 1.0 / ((double)BB * L1));
  k_pool1<<<(BB * P1 * 64 + 255) / 256, 256, 0, stream>>>(maxb, h1p, sc1, sh1, BB * P1 * 64);

  // ---- pack binarized weights (after pool1: these alias the maxbuf span) ----
  k_prep_wconv<<<656, 256, 0, stream>>>(w2, wp2, 64, 64);
  k_prep_wconv<<<1024, 256, 0, stream>>>(w3, wp3, 128, 64);
  k_prep_wconv<<<1024, 256, 0, stream>>>(w4, wp4, 128, 128);
  k_prep_wconv<<<1024, 256, 0, stream>>>(w5, wp5, 128, 128);
  k_sign8<<<2048, 256, 0, stream>>>(fw1, sfw1, 2048 * EMB);
  k_sign8<<<1024, 256, 0, stream>>>(fw2, sfw2, 1000 * 2048);

  // conv2 (MFMA)
  k_bconv_mfma<64, 64><<<dim3(82, 1, 64), 256, 0, stream>>>(h1p, wp2, h2, P1, L2);
  k_stats16<64><<<256, 256, 0, stream>>>(h2, st2, BB * L2);
  k_finalize_ll<<<1, 64, 0, stream>>>((const ll*)st2, g2, b2, sc2, sh2, 64, 1.0 / ((double)BB * L2));
  k_pool<<<(BB * 64 * P2 + 255) / 256, 256, 0, stream>>>(h2, h2p, sc2, sh2, 64, L2, P2, BB * 64 * P2);

  // conv3
  k_bconv_mfma<64, 128><<<dim3(26, 2, 64), 256, 0, stream>>>(h2p, wp3, h3, P2, L3);
  k_stats16<128><<<256, 256, 0, stream>>>(h3, st3, BB * L3);
  k_finalize_ll<<<1, 128, 0, stream>>>((const ll*)st3, g3, b3, sc3, sh3, 128, 1.0 / ((double)BB * L3));
  k_pool<<<(BB * 128 * P3 + 255) / 256, 256, 0, stream>>>(h3, h3p, sc3, sh3, 128, L3, P3, BB * 128 * P3);

  // conv4
  k_bconv_mfma<128, 128><<<dim3(8, 2, 64), 256, 0, stream>>>(h3p, wp4, h4, P3, L4);
  k_stats16<128><<<256, 256, 0, stream>>>(h4, st4, BB * L4);
  k_finalize_ll<<<1, 128, 0, stream>>>((const ll*)st4, g4, b4, sc4, sh4, 128, 1.0 / ((double)BB * L4));
  k_pool<<<(BB * 128 * P4 + 255) / 256, 256, 0, stream>>>(h4, h4p, sc4, sh4, 128, L4, P4, BB * 128 * P4);

  // conv5 (no pool; bn5+htanh+sign -> e1, re-transposed to [b][c*78+p])
  k_bconv_mfma<128, 128><<<dim3(2, 2, 64), 256, 0, stream>>>(h4p, wp5, h5, P4, L5);
  k_stats16<128><<<256, 256, 0, stream>>>(h5, st5, BB * L5);
  k_finalize_ll<<<1, 128, 0, stream>>>((const ll*)st5, g5, b5, sc5, sh5, 128, 1.0 / ((double)BB * L5));
  k_bn_sign_t<<<(BB * EMB + 255) / 256, 256, 0, stream>>>(h5, e1, sc5, sh5);

  // fc1 -> bn6 -> sign
  k_fc<EMB><<<dim3(8, BB), 256, 0, stream>>>(e1, sfw1, fc1o, 2048);
  k_fcstats<<<8, 256, 0, stream>>>(fc1o, g6, b6, sc6, sh6, 2048);
  k_bn_sign_fc<<<(BB * 2048 + 255) / 256, 256, 0, stream>>>(fc1o, e2, sc6, sh6, 2048, BB * 2048);

  // fc2 -> bn7 -> log_softmax
  k_fc<2048><<<dim3(4, BB), 256, 0, stream>>>(e2, sfw2, fc2o, 1000);
  k_fcstats<<<4, 256, 0, stream>>>(fc2o, g7, b7, sc7, sh7, 1000);
  k_lsm<<<64, 256, 0, stream>>>(fc2o, sc7, sh7, out);
}